// Round 1
// baseline (957.032 us; speedup 1.0000x reference)
//
#include <hip/hip_runtime.h>

// SparseGraphSAGE: 2-layer GCN + edge decoder, fp32 end-to-end.
// Pipeline: CSR build (count/scan/scatter) -> spmm -> gemm(relu) -> spmm ->
//           gemm -> gathered decoder gemm with fused final dot.

__global__ void k_count(const int* __restrict__ idx, const float* __restrict__ vals,
                        int* __restrict__ cnt, float* __restrict__ deg, int E){
  int e = blockIdx.x*blockDim.x + threadIdx.x;
  if (e >= E) return;
  int r = idx[2*e];
  atomicAdd(&cnt[r], 1);
  atomicAdd(&deg[r], vals[e]);
}

// single-block exclusive scan of cnt[0..N-1] (stored in rp), writes rp[0..N] and cursor copy
__global__ void k_scan(int* __restrict__ rp, int* __restrict__ cursor, int N){
  __shared__ int s[1024];
  int t = threadIdx.x;
  int running = 0;
  for (int base = 0; base < N; base += 1024){
    int i = base + t;
    int c = (i < N) ? rp[i] : 0;
    __syncthreads();
    s[t] = c;
    __syncthreads();
    #pragma unroll
    for (int off = 1; off < 1024; off <<= 1){
      int v = s[t];
      if (t >= off) v += s[t - off];
      __syncthreads();
      s[t] = v;
      __syncthreads();
    }
    int incl = s[t];
    int excl = running + incl - c;
    if (i < N){ rp[i] = excl; cursor[i] = excl; }
    running += s[1023];
  }
  if (t == 0) rp[N] = running;
}

__global__ void k_deginv(float* __restrict__ deg, int N){
  int i = blockIdx.x*blockDim.x + threadIdx.x;
  if (i < N) deg[i] = 1.0f / fmaxf(deg[i], 1.0f);
}

__global__ void k_scatter(const int* __restrict__ idx, const float* __restrict__ vals,
                          int* __restrict__ cursor, int* __restrict__ cols,
                          float* __restrict__ evals, int E){
  int e = blockIdx.x*blockDim.x + threadIdx.x;
  if (e >= E) return;
  int r = idx[2*e], c = idx[2*e+1];
  int p = atomicAdd(&cursor[r], 1);
  cols[p] = c;
  evals[p] = vals[e];
}

// out[r][:] = deg_inv[r] * sum_e vals[e] * X[cols[e]][:]   (2 rows per 256-thread block)
__global__ void k_spmm(const int* __restrict__ rp, const int* __restrict__ cols,
                       const float* __restrict__ evals, const float* __restrict__ X,
                       const float* __restrict__ deg_inv, float* __restrict__ out, int N){
  int r = blockIdx.x*2 + (threadIdx.x >> 7);
  int t = threadIdx.x & 127;
  if (r >= N) return;
  float acc = 0.f;
  int e0 = rp[r], e1 = rp[r+1];
  for (int e = e0; e < e1; ++e){
    int c = cols[e];
    float v = evals[e];
    acc = fmaf(v, X[(size_t)c*128 + t], acc);
  }
  out[(size_t)r*128 + t] = acc * deg_inv[r];
}

// Tiled fp32 GEMM: out(64-row tile x 128) = maybe_relu(X @ W + bias).
// GATHER: X row p = concat(h2[iu[p]], h2[iv[p]]) (K=256).
// FUSE:   epilogue computes out[p] = relu(row) . w2 + b2 (scalar per row).
template<int K, bool RELU, bool GATHER, bool FUSE>
__global__ __launch_bounds__(256)
void k_gemm(const float* __restrict__ X, const float* __restrict__ W,
            const float* __restrict__ bias, float* __restrict__ out, int M,
            const int* __restrict__ iu, const int* __restrict__ iv,
            const float* __restrict__ w2, const float* __restrict__ b2p)
{
  __shared__ float Xs[64][32];
  __shared__ float Ws[32][128];
  const int tid = threadIdx.x;
  const int c16 = tid & 15;
  const int r0  = (tid >> 4) * 4;
  const int brow = blockIdx.x * 64;

  float acc[4][8];
  #pragma unroll
  for (int i = 0; i < 4; ++i)
    #pragma unroll
    for (int j = 0; j < 8; ++j) acc[i][j] = 0.f;

  for (int ch = 0; ch < K/32; ++ch){
    #pragma unroll
    for (int i = 0; i < 8; ++i){           // 2048 X-tile elems / 256 thr
      int l = tid + i*256;
      int rr = l >> 5, kk = l & 31;
      int row = brow + rr; if (row >= M) row = M - 1;
      float x;
      if (GATHER){
        int kg = ch*32 + kk;               // 0..255
        int node = (kg < 128 ? iu : iv)[row];
        x = X[(size_t)node*128 + (kg & 127)];
      } else {
        x = X[(size_t)row*K + ch*32 + kk];
      }
      Xs[rr][kk] = x;
    }
    #pragma unroll
    for (int i = 0; i < 16; ++i){          // 4096 W-tile elems / 256 thr
      int l = tid + i*256;
      int kk = l >> 7, cc = l & 127;
      Ws[kk][cc] = W[(size_t)(ch*32 + kk)*128 + cc];
    }
    __syncthreads();
    #pragma unroll
    for (int k = 0; k < 32; ++k){
      float xv[4];
      #pragma unroll
      for (int i = 0; i < 4; ++i) xv[i] = Xs[r0 + i][k];
      #pragma unroll
      for (int j = 0; j < 8; ++j){
        float wv = Ws[k][c16 + 16*j];
        #pragma unroll
        for (int i = 0; i < 4; ++i) acc[i][j] = fmaf(xv[i], wv, acc[i][j]);
      }
    }
    __syncthreads();
  }

  if (!FUSE){
    #pragma unroll
    for (int i = 0; i < 4; ++i){
      int row = brow + r0 + i;
      if (row < M){
        #pragma unroll
        for (int j = 0; j < 8; ++j){
          int c = c16 + 16*j;
          float v = acc[i][j] + bias[c];
          if (RELU) v = fmaxf(v, 0.f);
          out[(size_t)row*128 + c] = v;
        }
      }
    }
  } else {
    float b2 = b2p[0];
    #pragma unroll
    for (int i = 0; i < 4; ++i){
      float part = 0.f;
      #pragma unroll
      for (int j = 0; j < 8; ++j){
        int c = c16 + 16*j;
        float v = acc[i][j] + bias[c];
        v = fmaxf(v, 0.f);
        part = fmaf(v, w2[c], part);
      }
      #pragma unroll
      for (int off = 1; off < 16; off <<= 1)
        part += __shfl_xor(part, off);
      int row = brow + r0 + i;
      if (c16 == 0 && row < M) out[row] = part + b2;
    }
  }
}

extern "C" void kernel_launch(void* const* d_in, const int* in_sizes, int n_in,
                              void* d_out, int out_size, void* d_ws, size_t ws_size,
                              hipStream_t stream){
  const int*   adj   = (const int*)  d_in[0];
  const float* av    = (const float*)d_in[1];
  const float* h     = (const float*)d_in[3];
  const int*   pos_u = (const int*)  d_in[4];
  const int*   pos_v = (const int*)  d_in[5];
  const int*   neg_u = (const int*)  d_in[6];
  const int*   neg_v = (const int*)  d_in[7];
  const float* W1    = (const float*)d_in[8];
  const float* b1    = (const float*)d_in[9];
  const float* W2    = (const float*)d_in[10];
  const float* b2    = (const float*)d_in[11];
  const float* Wd1   = (const float*)d_in[12];
  const float* bd1   = (const float*)d_in[13];
  const float* Wd2   = (const float*)d_in[14];
  const float* bd2   = (const float*)d_in[15];

  const int E = in_sizes[0] / 2;
  const int N = in_sizes[3] / 128;
  const int P = in_sizes[4];

  // workspace layout
  char* w = (char*)d_ws;
  int*   rp     = (int*)w;    w += (size_t)(N+1)*4;
  float* deg    = (float*)w;  w += (size_t)N*4;       // becomes deg_inv
  int*   cursor = (int*)w;    w += (size_t)N*4;
  int*   cols   = (int*)w;    w += (size_t)E*4;
  float* evals  = (float*)w;  w += (size_t)E*4;
  float* h1     = (float*)w;  w += (size_t)N*128*4;

  float* scores_pos = (float*)d_out;
  float* scores_neg = scores_pos + P;
  float* h2         = scores_neg + P;   // also used as spmm accumulator (safe: gemm blocks read/write only their own rows)

  // zero cnt (rp) + deg
  hipMemsetAsync(d_ws, 0, (size_t)(2*N + 1) * 4, stream);

  k_count  <<<(E+255)/256, 256, 0, stream>>>(adj, av, rp, deg, E);
  k_scan   <<<1, 1024, 0, stream>>>(rp, cursor, N);
  k_deginv <<<(N+255)/256, 256, 0, stream>>>(deg, N);
  k_scatter<<<(E+255)/256, 256, 0, stream>>>(adj, av, cursor, cols, evals, E);

  // layer 1: agg(h) -> h1
  k_spmm<<<(N+1)/2, 256, 0, stream>>>(rp, cols, evals, h, deg, h2, N);
  k_gemm<128,true ,false,false><<<(N+63)/64, 256, 0, stream>>>(h2, W1, b1, h1, N, nullptr, nullptr, nullptr, nullptr);

  // layer 2: agg(h1) -> h2 (in d_out), gemm in-place
  k_spmm<<<(N+1)/2, 256, 0, stream>>>(rp, cols, evals, h1, deg, h2, N);
  k_gemm<128,false,false,false><<<(N+63)/64, 256, 0, stream>>>(h2, W2, b2, h2, N, nullptr, nullptr, nullptr, nullptr);

  // decoder: pos and neg
  k_gemm<256,true ,true ,true ><<<(P+63)/64, 256, 0, stream>>>(h2, Wd1, bd1, scores_pos, P, pos_u, pos_v, Wd2, bd2);
  k_gemm<256,true ,true ,true ><<<(P+63)/64, 256, 0, stream>>>(h2, Wd1, bd1, scores_neg, P, neg_u, neg_v, Wd2, bd2);
}

// Round 2
// 827.142 us; speedup vs baseline: 1.1570x; 1.1570x over previous
//
#include <hip/hip_runtime.h>

// SparseGraphSAGE: 2-layer GCN + edge decoder, fp32 end-to-end.
// CSR build (count/scan/scatter) -> spmm -> gemm(relu) -> spmm -> gemm ->
// gathered decoder gemm with fused final dot.

__global__ void k_count(const int* __restrict__ idx, const float* __restrict__ vals,
                        int* __restrict__ cnt, float* __restrict__ deg, int E){
  int e = blockIdx.x*blockDim.x + threadIdx.x;
  if (e >= E) return;
  int2 rc = ((const int2*)idx)[e];
  atomicAdd(&cnt[rc.x], 1);
  atomicAdd(&deg[rc.x], vals[e]);
}

// single-block scan: per-thread chunk sum -> block scan -> sequential writeback
__global__ void k_scan(int* __restrict__ rp, int* __restrict__ cursor, int N){
  __shared__ int s[1024];
  int t = threadIdx.x;
  const int C = (N + 1023) / 1024;
  int lo = t*C, hi = lo + C; if (hi > N) hi = N; if (lo > N) lo = N;
  int sum = 0;
  for (int i = lo; i < hi; ++i) sum += rp[i];
  s[t] = sum;
  __syncthreads();
  #pragma unroll
  for (int off = 1; off < 1024; off <<= 1){
    int v = s[t];
    int u = (t >= off) ? s[t-off] : 0;
    __syncthreads();
    s[t] = v + u;
    __syncthreads();
  }
  int run = s[t] - sum;               // exclusive base for this chunk
  for (int i = lo; i < hi; ++i){
    int c = rp[i];
    rp[i] = run; cursor[i] = run;
    run += c;
  }
  if (t == 1023) rp[N] = s[1023];
}

__global__ void k_deginv(float* __restrict__ deg, int N){
  int i = blockIdx.x*blockDim.x + threadIdx.x;
  if (i < N) deg[i] = 1.0f / fmaxf(deg[i], 1.0f);
}

__global__ void k_scatter(const int* __restrict__ idx, const float* __restrict__ vals,
                          int* __restrict__ cursor, int* __restrict__ cols,
                          float* __restrict__ evals, int E){
  int e = blockIdx.x*blockDim.x + threadIdx.x;
  if (e >= E) return;
  int2 rc = ((const int2*)idx)[e];
  int p = atomicAdd(&cursor[rc.x], 1);
  cols[p] = rc.y;
  evals[p] = vals[e];
}

// out[r][:] = deg_inv[r] * sum_e vals[e] * X[cols[e]][:]
// 8 rows per 256-thread block; 32 lanes x float4 per row; 2-edge unroll.
__global__ void k_spmm(const int* __restrict__ rp, const int* __restrict__ cols,
                       const float* __restrict__ evals, const float* __restrict__ X,
                       const float* __restrict__ deg_inv, float* __restrict__ out, int N){
  int r = blockIdx.x*8 + (threadIdx.x >> 5);
  int t = threadIdx.x & 31;
  if (r >= N) return;
  float4 acc = make_float4(0.f, 0.f, 0.f, 0.f);
  int e0 = rp[r], e1 = rp[r+1];
  int e = e0;
  for (; e + 1 < e1; e += 2){
    int c0 = cols[e],   c1 = cols[e+1];
    float v0 = evals[e], v1 = evals[e+1];
    float4 x0 = *(const float4*)&X[(size_t)c0*128 + t*4];
    float4 x1 = *(const float4*)&X[(size_t)c1*128 + t*4];
    acc.x = fmaf(v0, x0.x, acc.x); acc.y = fmaf(v0, x0.y, acc.y);
    acc.z = fmaf(v0, x0.z, acc.z); acc.w = fmaf(v0, x0.w, acc.w);
    acc.x = fmaf(v1, x1.x, acc.x); acc.y = fmaf(v1, x1.y, acc.y);
    acc.z = fmaf(v1, x1.z, acc.z); acc.w = fmaf(v1, x1.w, acc.w);
  }
  if (e < e1){
    int c0 = cols[e]; float v0 = evals[e];
    float4 x0 = *(const float4*)&X[(size_t)c0*128 + t*4];
    acc.x = fmaf(v0, x0.x, acc.x); acc.y = fmaf(v0, x0.y, acc.y);
    acc.z = fmaf(v0, x0.z, acc.z); acc.w = fmaf(v0, x0.w, acc.w);
  }
  float di = deg_inv[r];
  float4 o = make_float4(acc.x*di, acc.y*di, acc.z*di, acc.w*di);
  *(float4*)&out[(size_t)r*128 + t*4] = o;
}

// Tiled fp32 GEMM: 128-row tile x 128 cols, 256 threads, 8x8 register tile.
// GATHER: X row p = concat(h2[iu[p]], h2[iv[p]]) (K=256).
// FUSE:   epilogue computes out[p] = relu(row) . w2 + b2 (scalar per row).
template<int K, bool RELU, bool GATHER, bool FUSE>
__global__ __launch_bounds__(256)
void k_gemm(const float* __restrict__ X, const float* __restrict__ W,
            const float* __restrict__ bias, float* __restrict__ out, int M,
            const int* __restrict__ iu, const int* __restrict__ iv,
            const float* __restrict__ w2, const float* __restrict__ b2p)
{
  __shared__ float Xs[128][33];   // +1 pad: row-bank decorrelation
  __shared__ float Ws[32][128];
  const int tid = threadIdx.x;
  const int c4  = tid & 15;       // cols 4*c4+{0..3} and +64
  const int r0  = (tid >> 4) * 8; // 8 rows
  const int brow = blockIdx.x * 128;

  float acc[8][8];
  #pragma unroll
  for (int i = 0; i < 8; ++i)
    #pragma unroll
    for (int j = 0; j < 8; ++j) acc[i][j] = 0.f;

  for (int ch = 0; ch < K/32; ++ch){
    #pragma unroll
    for (int i = 0; i < 16; ++i){          // 128x32 X tile / 256 thr
      int l = tid + i*256;
      int rr = l >> 5, kk = l & 31;
      int row = brow + rr; if (row >= M) row = M - 1;
      float x;
      if (GATHER){
        int kg = ch*32 + kk;               // 0..255
        int node = (kg < 128 ? iu : iv)[row];
        x = X[(size_t)node*128 + (kg & 127)];
      } else {
        x = X[(size_t)row*K + ch*32 + kk];
      }
      Xs[rr][kk] = x;
    }
    #pragma unroll
    for (int i = 0; i < 16; ++i){          // 32x128 W tile / 256 thr
      int l = tid + i*256;
      int kk = l >> 7, cc = l & 127;
      Ws[kk][cc] = W[(size_t)(ch*32 + kk)*128 + cc];
    }
    __syncthreads();
    #pragma unroll
    for (int k = 0; k < 32; ++k){
      float4 w0 = *(const float4*)&Ws[k][c4*4];
      float4 w1 = *(const float4*)&Ws[k][c4*4 + 64];
      #pragma unroll
      for (int i = 0; i < 8; ++i){
        float xv = Xs[r0 + i][k];
        acc[i][0] = fmaf(xv, w0.x, acc[i][0]);
        acc[i][1] = fmaf(xv, w0.y, acc[i][1]);
        acc[i][2] = fmaf(xv, w0.z, acc[i][2]);
        acc[i][3] = fmaf(xv, w0.w, acc[i][3]);
        acc[i][4] = fmaf(xv, w1.x, acc[i][4]);
        acc[i][5] = fmaf(xv, w1.y, acc[i][5]);
        acc[i][6] = fmaf(xv, w1.z, acc[i][6]);
        acc[i][7] = fmaf(xv, w1.w, acc[i][7]);
      }
    }
    __syncthreads();
  }

  if (!FUSE){
    float4 bb0 = *(const float4*)&bias[c4*4];
    float4 bb1 = *(const float4*)&bias[c4*4 + 64];
    #pragma unroll
    for (int i = 0; i < 8; ++i){
      int row = brow + r0 + i;
      if (row < M){
        float4 v0, v1;
        v0.x = acc[i][0] + bb0.x; v0.y = acc[i][1] + bb0.y;
        v0.z = acc[i][2] + bb0.z; v0.w = acc[i][3] + bb0.w;
        v1.x = acc[i][4] + bb1.x; v1.y = acc[i][5] + bb1.y;
        v1.z = acc[i][6] + bb1.z; v1.w = acc[i][7] + bb1.w;
        if (RELU){
          v0.x = fmaxf(v0.x, 0.f); v0.y = fmaxf(v0.y, 0.f);
          v0.z = fmaxf(v0.z, 0.f); v0.w = fmaxf(v0.w, 0.f);
          v1.x = fmaxf(v1.x, 0.f); v1.y = fmaxf(v1.y, 0.f);
          v1.z = fmaxf(v1.z, 0.f); v1.w = fmaxf(v1.w, 0.f);
        }
        *(float4*)&out[(size_t)row*128 + c4*4]      = v0;
        *(float4*)&out[(size_t)row*128 + c4*4 + 64] = v1;
      }
    }
  } else {
    float b2v = b2p[0];
    float4 bb0 = *(const float4*)&bias[c4*4];
    float4 bb1 = *(const float4*)&bias[c4*4 + 64];
    float4 wd0 = *(const float4*)&w2[c4*4];
    float4 wd1 = *(const float4*)&w2[c4*4 + 64];
    #pragma unroll
    for (int i = 0; i < 8; ++i){
      float part = 0.f;
      part = fmaf(fmaxf(acc[i][0] + bb0.x, 0.f), wd0.x, part);
      part = fmaf(fmaxf(acc[i][1] + bb0.y, 0.f), wd0.y, part);
      part = fmaf(fmaxf(acc[i][2] + bb0.z, 0.f), wd0.z, part);
      part = fmaf(fmaxf(acc[i][3] + bb0.w, 0.f), wd0.w, part);
      part = fmaf(fmaxf(acc[i][4] + bb1.x, 0.f), wd1.x, part);
      part = fmaf(fmaxf(acc[i][5] + bb1.y, 0.f), wd1.y, part);
      part = fmaf(fmaxf(acc[i][6] + bb1.z, 0.f), wd1.z, part);
      part = fmaf(fmaxf(acc[i][7] + bb1.w, 0.f), wd1.w, part);
      #pragma unroll
      for (int off = 1; off < 16; off <<= 1)
        part += __shfl_xor(part, off);
      int row = brow + r0 + i;
      if (c4 == 0 && row < M) out[row] = part + b2v;
    }
  }
}

extern "C" void kernel_launch(void* const* d_in, const int* in_sizes, int n_in,
                              void* d_out, int out_size, void* d_ws, size_t ws_size,
                              hipStream_t stream){
  const int*   adj   = (const int*)  d_in[0];
  const float* av    = (const float*)d_in[1];
  const float* h     = (const float*)d_in[3];
  const int*   pos_u = (const int*)  d_in[4];
  const int*   pos_v = (const int*)  d_in[5];
  const int*   neg_u = (const int*)  d_in[6];
  const int*   neg_v = (const int*)  d_in[7];
  const float* W1    = (const float*)d_in[8];
  const float* b1    = (const float*)d_in[9];
  const float* W2    = (const float*)d_in[10];
  const float* b2    = (const float*)d_in[11];
  const float* Wd1   = (const float*)d_in[12];
  const float* bd1   = (const float*)d_in[13];
  const float* Wd2   = (const float*)d_in[14];
  const float* bd2   = (const float*)d_in[15];

  const int E = in_sizes[0] / 2;
  const int N = in_sizes[3] / 128;
  const int P = in_sizes[4];

  char* w = (char*)d_ws;
  int*   rp     = (int*)w;    w += (size_t)(N+1)*4;
  float* deg    = (float*)w;  w += (size_t)N*4;       // becomes deg_inv
  int*   cursor = (int*)w;    w += (size_t)N*4;
  int*   cols   = (int*)w;    w += (size_t)E*4;
  float* evals  = (float*)w;  w += (size_t)E*4;
  float* h1     = (float*)w;  w += (size_t)N*128*4;

  float* scores_pos = (float*)d_out;
  float* scores_neg = scores_pos + P;
  float* h2         = scores_neg + P;   // spmm accumulator + final output

  hipMemsetAsync(d_ws, 0, (size_t)(2*N + 1) * 4, stream);

  k_count  <<<(E+255)/256, 256, 0, stream>>>(adj, av, rp, deg, E);
  k_scan   <<<1, 1024, 0, stream>>>(rp, cursor, N);
  k_deginv <<<(N+255)/256, 256, 0, stream>>>(deg, N);
  k_scatter<<<(E+255)/256, 256, 0, stream>>>(adj, av, cursor, cols, evals, E);

  // layer 1: agg(h) -> h2 (scratch use of out region), gemm -> h1
  k_spmm<<<(N+7)/8, 256, 0, stream>>>(rp, cols, evals, h, deg, h2, N);
  k_gemm<128,true ,false,false><<<(N+127)/128, 256, 0, stream>>>(h2, W1, b1, h1, N, nullptr, nullptr, nullptr, nullptr);

  // layer 2: agg(h1) -> h2, gemm in-place
  k_spmm<<<(N+7)/8, 256, 0, stream>>>(rp, cols, evals, h1, deg, h2, N);
  k_gemm<128,false,false,false><<<(N+127)/128, 256, 0, stream>>>(h2, W2, b2, h2, N, nullptr, nullptr, nullptr, nullptr);

  // decoder: pos and neg
  k_gemm<256,true ,true ,true ><<<(P+127)/128, 256, 0, stream>>>(h2, Wd1, bd1, scores_pos, P, pos_u, pos_v, Wd2, bd2);
  k_gemm<256,true ,true ,true ><<<(P+127)/128, 256, 0, stream>>>(h2, Wd1, bd1, scores_neg, P, neg_u, neg_v, Wd2, bd2);
}

// Round 3
// 587.666 us; speedup vs baseline: 1.6285x; 1.4075x over previous
//
#include <hip/hip_runtime.h>

// SparseGraphSAGE: CSR build -> spmm -> fp32 gemm(relu) -> spmm -> fp32 gemm
// -> bf16-MFMA gathered decoder with fused final dot.

typedef float  f32x4 __attribute__((ext_vector_type(4)));
typedef short  s16x8 __attribute__((ext_vector_type(8)));
typedef short  s16x4 __attribute__((ext_vector_type(4)));

__device__ inline short f2bf(float f){
  union { float f; unsigned u; } x; x.f = f;
  unsigned u = x.u;
  return (short)((u + 0x7FFFu + ((u >> 16) & 1u)) >> 16);   // RNE
}

__global__ void k_count(const int* __restrict__ idx, const float* __restrict__ vals,
                        int* __restrict__ cnt, float* __restrict__ deg, int E){
  int e = blockIdx.x*blockDim.x + threadIdx.x;
  if (e >= E) return;
  int2 rc = ((const int2*)idx)[e];
  atomicAdd(&cnt[rc.x], 1);
  atomicAdd(&deg[rc.x], vals[e]);
}

__global__ void k_scan(int* __restrict__ rp, int* __restrict__ cursor, int N){
  __shared__ int s[1024];
  int t = threadIdx.x;
  const int C = (N + 1023) / 1024;
  int lo = t*C, hi = lo + C; if (hi > N) hi = N; if (lo > N) lo = N;
  int sum = 0;
  for (int i = lo; i < hi; ++i) sum += rp[i];
  s[t] = sum;
  __syncthreads();
  #pragma unroll
  for (int off = 1; off < 1024; off <<= 1){
    int v = s[t];
    int u = (t >= off) ? s[t-off] : 0;
    __syncthreads();
    s[t] = v + u;
    __syncthreads();
  }
  int run = s[t] - sum;
  for (int i = lo; i < hi; ++i){
    int c = rp[i];
    rp[i] = run; cursor[i] = run;
    run += c;
  }
  if (t == 1023) rp[N] = s[1023];
}

__global__ void k_deginv(float* __restrict__ deg, int N){
  int i = blockIdx.x*blockDim.x + threadIdx.x;
  if (i < N) deg[i] = 1.0f / fmaxf(deg[i], 1.0f);
}

__global__ void k_scatter(const int* __restrict__ idx, const float* __restrict__ vals,
                          int* __restrict__ cursor, int* __restrict__ cols,
                          float* __restrict__ evals, int E){
  int e = blockIdx.x*blockDim.x + threadIdx.x;
  if (e >= E) return;
  int2 rc = ((const int2*)idx)[e];
  int p = atomicAdd(&cursor[rc.x], 1);
  cols[p] = rc.y;
  evals[p] = vals[e];
}

// out[r][:] = deg_inv[r] * sum_e vals[e] * X[cols[e]][:]
__global__ void k_spmm(const int* __restrict__ rp, const int* __restrict__ cols,
                       const float* __restrict__ evals, const float* __restrict__ X,
                       const float* __restrict__ deg_inv, float* __restrict__ out, int N){
  int r = blockIdx.x*8 + (threadIdx.x >> 5);
  int t = threadIdx.x & 31;
  if (r >= N) return;
  float4 acc = make_float4(0.f, 0.f, 0.f, 0.f);
  int e0 = rp[r], e1 = rp[r+1];
  int e = e0;
  for (; e + 1 < e1; e += 2){
    int c0 = cols[e],   c1 = cols[e+1];
    float v0 = evals[e], v1 = evals[e+1];
    float4 x0 = *(const float4*)&X[(size_t)c0*128 + t*4];
    float4 x1 = *(const float4*)&X[(size_t)c1*128 + t*4];
    acc.x = fmaf(v0, x0.x, acc.x); acc.y = fmaf(v0, x0.y, acc.y);
    acc.z = fmaf(v0, x0.z, acc.z); acc.w = fmaf(v0, x0.w, acc.w);
    acc.x = fmaf(v1, x1.x, acc.x); acc.y = fmaf(v1, x1.y, acc.y);
    acc.z = fmaf(v1, x1.z, acc.z); acc.w = fmaf(v1, x1.w, acc.w);
  }
  if (e < e1){
    int c0 = cols[e]; float v0 = evals[e];
    float4 x0 = *(const float4*)&X[(size_t)c0*128 + t*4];
    acc.x = fmaf(v0, x0.x, acc.x); acc.y = fmaf(v0, x0.y, acc.y);
    acc.z = fmaf(v0, x0.z, acc.z); acc.w = fmaf(v0, x0.w, acc.w);
  }
  float di = deg_inv[r];
  float4 o = make_float4(acc.x*di, acc.y*di, acc.z*di, acc.w*di);
  *(float4*)&out[(size_t)r*128 + t*4] = o;
}

// fp32 layer GEMM: 128 rows x 128 cols per block, K=128, Xs transposed [k][row].
template<bool RELU>
__global__ __launch_bounds__(256)
void k_gemm(const float* __restrict__ X, const float* __restrict__ W,
            const float* __restrict__ bias, float* __restrict__ out, int M)
{
  __shared__ float Xs[32][132];   // [k][row], +4 pad keeps b128 reads aligned
  __shared__ float Ws[32][128];
  const int tid = threadIdx.x;
  const int c4 = tid & 15;
  const int r0 = (tid >> 4) * 8;
  const int brow = blockIdx.x * 128;

  float acc[8][8];
  #pragma unroll
  for (int i = 0; i < 8; ++i)
    #pragma unroll
    for (int j = 0; j < 8; ++j) acc[i][j] = 0.f;

  for (int ch = 0; ch < 4; ++ch){
    #pragma unroll
    for (int i = 0; i < 16; ++i){
      int l = tid + i*256;
      int rr = l >> 5, kk = l & 31;
      int row = brow + rr; if (row >= M) row = M - 1;
      Xs[kk][rr] = X[(size_t)row*128 + ch*32 + kk];
    }
    #pragma unroll
    for (int i = 0; i < 16; ++i){
      int l = tid + i*256;
      int kk = l >> 7, cc = l & 127;
      Ws[kk][cc] = W[(size_t)(ch*32 + kk)*128 + cc];
    }
    __syncthreads();
    #pragma unroll
    for (int k = 0; k < 32; ++k){
      float4 x0 = *(const float4*)&Xs[k][r0];
      float4 x1 = *(const float4*)&Xs[k][r0 + 4];
      float4 w0 = *(const float4*)&Ws[k][c4*4];
      float4 w1 = *(const float4*)&Ws[k][c4*4 + 64];
      float xv[8] = {x0.x,x0.y,x0.z,x0.w,x1.x,x1.y,x1.z,x1.w};
      float wv[8] = {w0.x,w0.y,w0.z,w0.w,w1.x,w1.y,w1.z,w1.w};
      #pragma unroll
      for (int i = 0; i < 8; ++i)
        #pragma unroll
        for (int j = 0; j < 8; ++j)
          acc[i][j] = fmaf(xv[i], wv[j], acc[i][j]);
    }
    __syncthreads();
  }

  float4 bb0 = *(const float4*)&bias[c4*4];
  float4 bb1 = *(const float4*)&bias[c4*4 + 64];
  #pragma unroll
  for (int i = 0; i < 8; ++i){
    int row = brow + r0 + i;
    if (row < M){
      float v[8];
      v[0]=acc[i][0]+bb0.x; v[1]=acc[i][1]+bb0.y; v[2]=acc[i][2]+bb0.z; v[3]=acc[i][3]+bb0.w;
      v[4]=acc[i][4]+bb1.x; v[5]=acc[i][5]+bb1.y; v[6]=acc[i][6]+bb1.z; v[7]=acc[i][7]+bb1.w;
      if (RELU){
        #pragma unroll
        for (int j = 0; j < 8; ++j) v[j] = fmaxf(v[j], 0.f);
      }
      *(float4*)&out[(size_t)row*128 + c4*4]      = make_float4(v[0],v[1],v[2],v[3]);
      *(float4*)&out[(size_t)row*128 + c4*4 + 64] = make_float4(v[4],v[5],v[6],v[7]);
    }
  }
}

// h2 (fp32) -> bf16 bits
__global__ void k_h2bf16(const float4* __restrict__ src, short* __restrict__ dst, int n4){
  int i = blockIdx.x*blockDim.x + threadIdx.x;
  if (i >= n4) return;
  float4 v = src[i];
  s16x4 o; o[0]=f2bf(v.x); o[1]=f2bf(v.y); o[2]=f2bf(v.z); o[3]=f2bf(v.w);
  *(s16x4*)&dst[(size_t)i*4] = o;
}

// Pack Wd1 (256x128 fp32) into MFMA B-fragment order, bf16:
// WdP[((j*8+kk)*64 + lane)*8 + b] = bf16(Wd1[kk*32 + 8*(lane>>4) + b][j*16 + (lane&15)])
__global__ void k_packW(const float* __restrict__ Wd1, short* __restrict__ WdP){
  int idx = blockIdx.x*blockDim.x + threadIdx.x;   // 32768 total
  int b = idx & 7, lane = (idx >> 3) & 63, kk = (idx >> 9) & 7, j = (idx >> 12) & 7;
  int row = kk*32 + 8*(lane >> 4) + b;
  int col = j*16 + (lane & 15);
  WdP[idx] = f2bf(Wd1[row*128 + col]);
}

// Decoder: out[p] = relu(concat(h2[u],h2[v]) @ Wd1 + bd1) @ Wd2 + bd2
// 128 rows/block, 4 waves, each wave: 2 A-row-tiles x 8 col-tiles, K=256.
// MFMA 16x16x32 bf16; A frags gathered straight from h2b; B frags from packed WdP.
__global__ __launch_bounds__(256)
void k_decode(const short* __restrict__ h2b, const short* __restrict__ WdP,
              const float* __restrict__ bd1, const float* __restrict__ wd2,
              const float* __restrict__ bd2, const int* __restrict__ iu,
              const int* __restrict__ iv, float* __restrict__ out, int P)
{
  const int wave = threadIdx.x >> 6;
  const int lane = threadIdx.x & 63;
  const int l15 = lane & 15, lg = lane >> 4;
  const int wbase = blockIdx.x*128 + wave*32;

  int ra0 = wbase + l15;      if (ra0 >= P) ra0 = P - 1;
  int ra1 = wbase + 16 + l15; if (ra1 >= P) ra1 = P - 1;
  int u0 = iu[ra0], v0 = iv[ra0];
  int u1 = iu[ra1], v1 = iv[ra1];

  s16x8 a0[8], a1[8];
  #pragma unroll
  for (int kk = 0; kk < 8; ++kk){
    int kg = kk*32 + 8*lg;                       // 0..255, 16B-aligned slot
    const short* s0 = (kg < 128) ? h2b + (size_t)u0*128 + kg
                                 : h2b + (size_t)v0*128 + (kg - 128);
    const short* s1 = (kg < 128) ? h2b + (size_t)u1*128 + kg
                                 : h2b + (size_t)v1*128 + (kg - 128);
    a0[kk] = *(const s16x8*)s0;
    a1[kk] = *(const s16x8*)s1;
  }

  const s16x8* Wp = (const s16x8*)WdP;
  f32x4 acc0[8], acc1[8];
  #pragma unroll
  for (int j = 0; j < 8; ++j){
    acc0[j] = (f32x4){0.f,0.f,0.f,0.f};
    acc1[j] = (f32x4){0.f,0.f,0.f,0.f};
  }

  #pragma unroll
  for (int j = 0; j < 8; ++j){
    #pragma unroll
    for (int kk = 0; kk < 8; ++kk){
      s16x8 b = Wp[(j*8 + kk)*64 + lane];
      acc0[j] = __builtin_amdgcn_mfma_f32_16x16x32_bf16(a0[kk], b, acc0[j], 0, 0, 0);
      acc1[j] = __builtin_amdgcn_mfma_f32_16x16x32_bf16(a1[kk], b, acc1[j], 0, 0, 0);
    }
  }

  // D: col = j*16 + l15, rows = wbase(+16) + 4*lg + r
  float part0[4] = {0,0,0,0}, part1[4] = {0,0,0,0};
  #pragma unroll
  for (int j = 0; j < 8; ++j){
    int col = j*16 + l15;
    float bb = bd1[col], ww = wd2[col];
    #pragma unroll
    for (int r = 0; r < 4; ++r){
      part0[r] = fmaf(fmaxf(acc0[j][r] + bb, 0.f), ww, part0[r]);
      part1[r] = fmaf(fmaxf(acc1[j][r] + bb, 0.f), ww, part1[r]);
    }
  }
  #pragma unroll
  for (int off = 1; off < 16; off <<= 1){
    #pragma unroll
    for (int r = 0; r < 4; ++r){
      part0[r] += __shfl_xor(part0[r], off);
      part1[r] += __shfl_xor(part1[r], off);
    }
  }
  if (l15 == 0){
    float b2v = bd2[0];
    int m0 = wbase + 4*lg, m1 = wbase + 16 + 4*lg;
    #pragma unroll
    for (int r = 0; r < 4; ++r){
      if (m0 + r < P) out[m0 + r] = part0[r] + b2v;
      if (m1 + r < P) out[m1 + r] = part1[r] + b2v;
    }
  }
}

extern "C" void kernel_launch(void* const* d_in, const int* in_sizes, int n_in,
                              void* d_out, int out_size, void* d_ws, size_t ws_size,
                              hipStream_t stream){
  const int*   adj   = (const int*)  d_in[0];
  const float* av    = (const float*)d_in[1];
  const float* h     = (const float*)d_in[3];
  const int*   pos_u = (const int*)  d_in[4];
  const int*   pos_v = (const int*)  d_in[5];
  const int*   neg_u = (const int*)  d_in[6];
  const int*   neg_v = (const int*)  d_in[7];
  const float* W1    = (const float*)d_in[8];
  const float* b1    = (const float*)d_in[9];
  const float* W2    = (const float*)d_in[10];
  const float* b2    = (const float*)d_in[11];
  const float* Wd1   = (const float*)d_in[12];
  const float* bd1   = (const float*)d_in[13];
  const float* Wd2   = (const float*)d_in[14];
  const float* bd2   = (const float*)d_in[15];

  const int E = in_sizes[0] / 2;
  const int N = in_sizes[3] / 128;
  const int P = in_sizes[4];

  auto al = [](size_t x){ return (x + 255) & ~(size_t)255; };
  char* base = (char*)d_ws;
  size_t off = 0;
  int*   rp     = (int*)(base + off);   off = al(off + (size_t)(N+1)*4);
  float* deg    = (float*)(base + off); off = al(off + (size_t)N*4);
  int*   cursor = (int*)(base + off);   off = al(off + (size_t)N*4);
  int*   cols   = (int*)(base + off);   off = al(off + (size_t)E*4);
  float* evals  = (float*)(base + off); off = al(off + (size_t)E*4);
  size_t h1_off = off;
  float* h1     = (float*)(base + off); off = al(off + (size_t)N*128*4);
  // h1 region reused after layer-2 spmm consumes h1:
  short* h2b    = (short*)(base + h1_off);
  short* WdP    = (short*)(base + al(h1_off + (size_t)N*128*2));

  float* scores_pos = (float*)d_out;
  float* scores_neg = scores_pos + P;
  float* h2         = scores_neg + P;   // spmm accumulator + final fp32 output

  // zero rp (cnt) + deg
  hipMemsetAsync(rp, 0, (size_t)(N+1)*4, stream);
  hipMemsetAsync(deg, 0, (size_t)N*4, stream);

  k_count  <<<(E+255)/256, 256, 0, stream>>>(adj, av, rp, deg, E);
  k_scan   <<<1, 1024, 0, stream>>>(rp, cursor, N);
  k_deginv <<<(N+255)/256, 256, 0, stream>>>(deg, N);
  k_scatter<<<(E+255)/256, 256, 0, stream>>>(adj, av, cursor, cols, evals, E);

  // layer 1
  k_spmm<<<(N+7)/8, 256, 0, stream>>>(rp, cols, evals, h, deg, h2, N);
  k_gemm<true ><<<(N+127)/128, 256, 0, stream>>>(h2, W1, b1, h1, N);

  // layer 2 (h1 dead after spmm; gemm in-place on h2)
  k_spmm<<<(N+7)/8, 256, 0, stream>>>(rp, cols, evals, h1, deg, h2, N);
  k_gemm<false><<<(N+127)/128, 256, 0, stream>>>(h2, W2, b2, h2, N);

  // decoder prep
  k_h2bf16<<<((N*128/4)+255)/256, 256, 0, stream>>>((const float4*)h2, h2b, N*128/4);
  k_packW <<<128, 256, 0, stream>>>(Wd1, WdP);

  // decode
  k_decode<<<(P+127)/128, 256, 0, stream>>>(h2b, WdP, bd1, Wd2, bd2, pos_u, pos_v, scores_pos, P);
  k_decode<<<(P+127)/128, 256, 0, stream>>>(h2b, WdP, bd1, Wd2, bd2, neg_u, neg_v, scores_neg, P);
}

// Round 4
// 439.606 us; speedup vs baseline: 2.1770x; 1.3368x over previous
//
#include <hip/hip_runtime.h>

// SparseGraphSAGE: CSR build (count -> hierarchical scan -> scatter) ->
// spmm(fused deg) -> fp32 gemm(relu) -> spmm -> fp32 gemm(+bf16 emit) ->
// bf16-MFMA gathered decoder with fused final dot.

typedef float  f32x4 __attribute__((ext_vector_type(4)));
typedef short  s16x8 __attribute__((ext_vector_type(8)));
typedef short  s16x4 __attribute__((ext_vector_type(4)));

__device__ inline short f2bf(float f){
  union { float f; unsigned u; } x; x.f = f;
  unsigned u = x.u;
  return (short)((u + 0x7FFFu + ((u >> 16) & 1u)) >> 16);   // RNE
}

__global__ void k_count(const int* __restrict__ idx, int* __restrict__ cnt, int E){
  int e = blockIdx.x*blockDim.x + threadIdx.x;
  if (e >= E) return;
  int2 rc = ((const int2*)idx)[e];
  atomicAdd(&cnt[rc.x], 1);
}

// per-256-block sum of cnt
__global__ void k_blocksum(const int* __restrict__ rp, int* __restrict__ bsum, int N){
  int i = blockIdx.x*256 + threadIdx.x;
  int c = (i < N) ? rp[i] : 0;
  #pragma unroll
  for (int off = 1; off < 64; off <<= 1) c += __shfl_xor(c, off);
  __shared__ int s[4];
  if ((threadIdx.x & 63) == 0) s[threadIdx.x >> 6] = c;
  __syncthreads();
  if (threadIdx.x == 0) bsum[blockIdx.x] = s[0] + s[1] + s[2] + s[3];
}

// 1-block exclusive scan of B block sums -> boff; total -> *rpN
__global__ void k_scanb(const int* __restrict__ bsum, int* __restrict__ boff,
                        int* __restrict__ rpN, int B){
  __shared__ int s[256];
  int t = threadIdx.x;
  int run = 0;
  for (int base = 0; base < B; base += 256){
    int c = (base + t < B) ? bsum[base + t] : 0;
    s[t] = c;
    __syncthreads();
    #pragma unroll
    for (int off = 1; off < 256; off <<= 1){
      int v = s[t];
      int u = (t >= off) ? s[t-off] : 0;
      __syncthreads();
      s[t] = v + u;
      __syncthreads();
    }
    if (base + t < B) boff[base + t] = run + s[t] - c;
    run += s[255];
    __syncthreads();
  }
  if (t == 0) rpN[0] = run;
}

// per-block local exclusive scan + boff -> rp, cursor
__global__ void k_addoff(int* __restrict__ rp, int* __restrict__ cursor,
                         const int* __restrict__ boff, int N){
  __shared__ int s[256];
  int t = threadIdx.x;
  int i = blockIdx.x*256 + t;
  int c = (i < N) ? rp[i] : 0;
  s[t] = c;
  __syncthreads();
  #pragma unroll
  for (int off = 1; off < 256; off <<= 1){
    int v = s[t];
    int u = (t >= off) ? s[t-off] : 0;
    __syncthreads();
    s[t] = v + u;
    __syncthreads();
  }
  int excl = s[t] - c + boff[blockIdx.x];
  if (i < N){ rp[i] = excl; cursor[i] = excl; }
}

__global__ void k_scatter(const int* __restrict__ idx, const float* __restrict__ vals,
                          int* __restrict__ cursor, int* __restrict__ cols,
                          float* __restrict__ evals, int E){
  int e = blockIdx.x*blockDim.x + threadIdx.x;
  if (e >= E) return;
  int2 rc = ((const int2*)idx)[e];
  int p = atomicAdd(&cursor[rc.x], 1);
  cols[p] = rc.y;
  evals[p] = vals[e];
}

// out[r][:] = (1/clip(sum v,1)) * sum_e v_e * X[cols[e]][:]
// deg computed on the fly from evals (row's values are contiguous in CSR).
__global__ void k_spmm(const int* __restrict__ rp, const int* __restrict__ cols,
                       const float* __restrict__ evals, const float* __restrict__ X,
                       float* __restrict__ out, int N){
  int r = blockIdx.x*8 + (threadIdx.x >> 5);
  int t = threadIdx.x & 31;
  if (r >= N) return;
  float4 acc = make_float4(0.f, 0.f, 0.f, 0.f);
  float vsum = 0.f;
  int e0 = rp[r], e1 = rp[r+1];
  int e = e0;
  for (; e + 1 < e1; e += 2){
    int c0 = cols[e],   c1 = cols[e+1];
    float v0 = evals[e], v1 = evals[e+1];
    float4 x0 = *(const float4*)&X[(size_t)c0*128 + t*4];
    float4 x1 = *(const float4*)&X[(size_t)c1*128 + t*4];
    vsum += v0 + v1;
    acc.x = fmaf(v0, x0.x, acc.x); acc.y = fmaf(v0, x0.y, acc.y);
    acc.z = fmaf(v0, x0.z, acc.z); acc.w = fmaf(v0, x0.w, acc.w);
    acc.x = fmaf(v1, x1.x, acc.x); acc.y = fmaf(v1, x1.y, acc.y);
    acc.z = fmaf(v1, x1.z, acc.z); acc.w = fmaf(v1, x1.w, acc.w);
  }
  if (e < e1){
    int c0 = cols[e]; float v0 = evals[e];
    float4 x0 = *(const float4*)&X[(size_t)c0*128 + t*4];
    vsum += v0;
    acc.x = fmaf(v0, x0.x, acc.x); acc.y = fmaf(v0, x0.y, acc.y);
    acc.z = fmaf(v0, x0.z, acc.z); acc.w = fmaf(v0, x0.w, acc.w);
  }
  float di = 1.0f / fmaxf(vsum, 1.0f);
  float4 o = make_float4(acc.x*di, acc.y*di, acc.z*di, acc.w*di);
  *(float4*)&out[(size_t)r*128 + t*4] = o;
}

// fp32 layer GEMM: 128 rows x 128 cols per block, K=128, Xs transposed [k][row].
// EMIT_BF16: also write bf16 copy of the output (for the MFMA decoder).
template<bool RELU, bool EMIT_BF16>
__global__ __launch_bounds__(256)
void k_gemm(const float* __restrict__ X, const float* __restrict__ W,
            const float* __restrict__ bias, float* __restrict__ out,
            short* __restrict__ out_bf, int M)
{
  __shared__ float Xs[32][132];
  __shared__ float Ws[32][128];
  const int tid = threadIdx.x;
  const int c4 = tid & 15;
  const int r0 = (tid >> 4) * 8;
  const int brow = blockIdx.x * 128;

  float acc[8][8];
  #pragma unroll
  for (int i = 0; i < 8; ++i)
    #pragma unroll
    for (int j = 0; j < 8; ++j) acc[i][j] = 0.f;

  for (int ch = 0; ch < 4; ++ch){
    #pragma unroll
    for (int i = 0; i < 16; ++i){
      int l = tid + i*256;
      int rr = l >> 5, kk = l & 31;
      int row = brow + rr; if (row >= M) row = M - 1;
      Xs[kk][rr] = X[(size_t)row*128 + ch*32 + kk];
    }
    #pragma unroll
    for (int i = 0; i < 16; ++i){
      int l = tid + i*256;
      int kk = l >> 7, cc = l & 127;
      Ws[kk][cc] = W[(size_t)(ch*32 + kk)*128 + cc];
    }
    __syncthreads();
    #pragma unroll
    for (int k = 0; k < 32; ++k){
      float4 x0 = *(const float4*)&Xs[k][r0];
      float4 x1 = *(const float4*)&Xs[k][r0 + 4];
      float4 w0 = *(const float4*)&Ws[k][c4*4];
      float4 w1 = *(const float4*)&Ws[k][c4*4 + 64];
      float xv[8] = {x0.x,x0.y,x0.z,x0.w,x1.x,x1.y,x1.z,x1.w};
      float wv[8] = {w0.x,w0.y,w0.z,w0.w,w1.x,w1.y,w1.z,w1.w};
      #pragma unroll
      for (int i = 0; i < 8; ++i)
        #pragma unroll
        for (int j = 0; j < 8; ++j)
          acc[i][j] = fmaf(xv[i], wv[j], acc[i][j]);
    }
    __syncthreads();
  }

  float4 bb0 = *(const float4*)&bias[c4*4];
  float4 bb1 = *(const float4*)&bias[c4*4 + 64];
  #pragma unroll
  for (int i = 0; i < 8; ++i){
    int row = brow + r0 + i;
    if (row < M){
      float v[8];
      v[0]=acc[i][0]+bb0.x; v[1]=acc[i][1]+bb0.y; v[2]=acc[i][2]+bb0.z; v[3]=acc[i][3]+bb0.w;
      v[4]=acc[i][4]+bb1.x; v[5]=acc[i][5]+bb1.y; v[6]=acc[i][6]+bb1.z; v[7]=acc[i][7]+bb1.w;
      if (RELU){
        #pragma unroll
        for (int j = 0; j < 8; ++j) v[j] = fmaxf(v[j], 0.f);
      }
      *(float4*)&out[(size_t)row*128 + c4*4]      = make_float4(v[0],v[1],v[2],v[3]);
      *(float4*)&out[(size_t)row*128 + c4*4 + 64] = make_float4(v[4],v[5],v[6],v[7]);
      if (EMIT_BF16){
        s16x4 o0, o1;
        #pragma unroll
        for (int j = 0; j < 4; ++j){ o0[j] = f2bf(v[j]); o1[j] = f2bf(v[4+j]); }
        *(s16x4*)&out_bf[(size_t)row*128 + c4*4]      = o0;
        *(s16x4*)&out_bf[(size_t)row*128 + c4*4 + 64] = o1;
      }
    }
  }
}

// Pack Wd1 (256x128 fp32) into MFMA B-fragment order, bf16.
__global__ void k_packW(const float* __restrict__ Wd1, short* __restrict__ WdP){
  int idx = blockIdx.x*blockDim.x + threadIdx.x;   // 32768 total
  int b = idx & 7, lane = (idx >> 3) & 63, kk = (idx >> 9) & 7, j = (idx >> 12) & 7;
  int row = kk*32 + 8*(lane >> 4) + b;
  int col = j*16 + (lane & 15);
  WdP[idx] = f2bf(Wd1[row*128 + col]);
}

// Decoder: out[p] = relu(concat(h2[u],h2[v]) @ Wd1 + bd1) @ Wd2 + bd2
__global__ __launch_bounds__(256)
void k_decode(const short* __restrict__ h2b, const short* __restrict__ WdP,
              const float* __restrict__ bd1, const float* __restrict__ wd2,
              const float* __restrict__ bd2, const int* __restrict__ iu,
              const int* __restrict__ iv, float* __restrict__ out, int P)
{
  const int wave = threadIdx.x >> 6;
  const int lane = threadIdx.x & 63;
  const int l15 = lane & 15, lg = lane >> 4;
  const int wbase = blockIdx.x*128 + wave*32;

  int ra0 = wbase + l15;      if (ra0 >= P) ra0 = P - 1;
  int ra1 = wbase + 16 + l15; if (ra1 >= P) ra1 = P - 1;
  int u0 = iu[ra0], v0 = iv[ra0];
  int u1 = iu[ra1], v1 = iv[ra1];

  s16x8 a0[8], a1[8];
  #pragma unroll
  for (int kk = 0; kk < 8; ++kk){
    int kg = kk*32 + 8*lg;
    const short* s0 = (kg < 128) ? h2b + (size_t)u0*128 + kg
                                 : h2b + (size_t)v0*128 + (kg - 128);
    const short* s1 = (kg < 128) ? h2b + (size_t)u1*128 + kg
                                 : h2b + (size_t)v1*128 + (kg - 128);
    a0[kk] = *(const s16x8*)s0;
    a1[kk] = *(const s16x8*)s1;
  }

  const s16x8* Wp = (const s16x8*)WdP;
  f32x4 acc0[8], acc1[8];
  #pragma unroll
  for (int j = 0; j < 8; ++j){
    acc0[j] = (f32x4){0.f,0.f,0.f,0.f};
    acc1[j] = (f32x4){0.f,0.f,0.f,0.f};
  }

  #pragma unroll
  for (int j = 0; j < 8; ++j){
    #pragma unroll
    for (int kk = 0; kk < 8; ++kk){
      s16x8 b = Wp[(j*8 + kk)*64 + lane];
      acc0[j] = __builtin_amdgcn_mfma_f32_16x16x32_bf16(a0[kk], b, acc0[j], 0, 0, 0);
      acc1[j] = __builtin_amdgcn_mfma_f32_16x16x32_bf16(a1[kk], b, acc1[j], 0, 0, 0);
    }
  }

  float part0[4] = {0,0,0,0}, part1[4] = {0,0,0,0};
  #pragma unroll
  for (int j = 0; j < 8; ++j){
    int col = j*16 + l15;
    float bb = bd1[col], ww = wd2[col];
    #pragma unroll
    for (int r = 0; r < 4; ++r){
      part0[r] = fmaf(fmaxf(acc0[j][r] + bb, 0.f), ww, part0[r]);
      part1[r] = fmaf(fmaxf(acc1[j][r] + bb, 0.f), ww, part1[r]);
    }
  }
  #pragma unroll
  for (int off = 1; off < 16; off <<= 1){
    #pragma unroll
    for (int r = 0; r < 4; ++r){
      part0[r] += __shfl_xor(part0[r], off);
      part1[r] += __shfl_xor(part1[r], off);
    }
  }
  if (l15 == 0){
    float b2v = bd2[0];
    int m0 = wbase + 4*lg, m1 = wbase + 16 + 4*lg;
    #pragma unroll
    for (int r = 0; r < 4; ++r){
      if (m0 + r < P) out[m0 + r] = part0[r] + b2v;
      if (m1 + r < P) out[m1 + r] = part1[r] + b2v;
    }
  }
}

extern "C" void kernel_launch(void* const* d_in, const int* in_sizes, int n_in,
                              void* d_out, int out_size, void* d_ws, size_t ws_size,
                              hipStream_t stream){
  const int*   adj   = (const int*)  d_in[0];
  const float* av    = (const float*)d_in[1];
  const float* h     = (const float*)d_in[3];
  const int*   pos_u = (const int*)  d_in[4];
  const int*   pos_v = (const int*)  d_in[5];
  const int*   neg_u = (const int*)  d_in[6];
  const int*   neg_v = (const int*)  d_in[7];
  const float* W1    = (const float*)d_in[8];
  const float* b1    = (const float*)d_in[9];
  const float* W2    = (const float*)d_in[10];
  const float* b2    = (const float*)d_in[11];
  const float* Wd1   = (const float*)d_in[12];
  const float* bd1   = (const float*)d_in[13];
  const float* Wd2   = (const float*)d_in[14];
  const float* bd2   = (const float*)d_in[15];

  const int E = in_sizes[0] / 2;
  const int N = in_sizes[3] / 128;
  const int P = in_sizes[4];
  const int NB = (N + 255) / 256;

  auto al = [](size_t x){ return (x + 255) & ~(size_t)255; };
  char* base = (char*)d_ws;
  size_t off = 0;
  int*   rp     = (int*)(base + off);   off = al(off + (size_t)(N+1)*4);
  int*   cursor = (int*)(base + off);   off = al(off + (size_t)N*4);
  int*   bsum   = (int*)(base + off);   off = al(off + (size_t)NB*4);
  int*   boff   = (int*)(base + off);   off = al(off + (size_t)NB*4);
  int*   cols   = (int*)(base + off);   off = al(off + (size_t)E*4);
  float* evals  = (float*)(base + off); off = al(off + (size_t)E*4);
  size_t h1_off = off;
  float* h1     = (float*)(base + off); off = al(off + (size_t)N*128*4);
  // h1 region reused after layer-2 spmm consumes h1:
  short* h2b    = (short*)(base + h1_off);
  short* WdP    = (short*)(base + al(h1_off + (size_t)N*128*2));

  float* scores_pos = (float*)d_out;
  float* scores_neg = scores_pos + P;
  float* h2         = scores_neg + P;   // spmm accumulator + final fp32 output

  hipMemsetAsync(rp, 0, (size_t)(N+1)*4, stream);

  k_count   <<<(E+255)/256, 256, 0, stream>>>(adj, rp, E);
  k_blocksum<<<NB, 256, 0, stream>>>(rp, bsum, N);
  k_scanb   <<<1, 256, 0, stream>>>(bsum, boff, rp + N, NB);
  k_addoff  <<<NB, 256, 0, stream>>>(rp, cursor, boff, N);
  k_scatter <<<(E+255)/256, 256, 0, stream>>>(adj, av, cursor, cols, evals, E);

  // layer 1
  k_spmm<<<(N+7)/8, 256, 0, stream>>>(rp, cols, evals, h, h2, N);
  k_gemm<true , false><<<(N+127)/128, 256, 0, stream>>>(h2, W1, b1, h1, nullptr, N);

  // layer 2 (h1 dead after spmm; gemm in-place on h2, also emits bf16 copy)
  k_spmm<<<(N+7)/8, 256, 0, stream>>>(rp, cols, evals, h1, h2, N);
  k_gemm<false, true ><<<(N+127)/128, 256, 0, stream>>>(h2, W2, b2, h2, h2b, N);

  // decoder
  k_packW <<<128, 256, 0, stream>>>(Wd1, WdP);
  k_decode<<<(P+127)/128, 256, 0, stream>>>(h2b, WdP, bd1, Wd2, bd2, pos_u, pos_v, scores_pos, P);
  k_decode<<<(P+127)/128, 256, 0, stream>>>(h2b, WdP, bd1, Wd2, bd2, neg_u, neg_v, scores_neg, P);
}

// Round 6
// 407.621 us; speedup vs baseline: 2.3478x; 1.0785x over previous
//
#include <hip/hip_runtime.h>

// SparseGraphSAGE: CSR build (count -> hierarchical scan -> scatter) ->
// spmm(fused deg) -> split-bf16 MFMA gemm(relu) -> spmm -> MFMA gemm(+bf16 emit)
// -> bf16-MFMA gathered decoder with fused final dot.
// NOTE: WdP has a DEDICATED slot (round-5 bug: it aliased h1 and was clobbered).

typedef float  f32x4 __attribute__((ext_vector_type(4)));
typedef short  s16x8 __attribute__((ext_vector_type(8)));
typedef short  s16x4 __attribute__((ext_vector_type(4)));

__device__ inline short f2bf(float f){
  union { float f; unsigned u; } x; x.f = f;
  unsigned u = x.u;
  return (short)((u + 0x7FFFu + ((u >> 16) & 1u)) >> 16);   // RNE
}
__device__ inline float bf2f(short h){
  union { unsigned u; float f; } c; c.u = ((unsigned)(unsigned short)h) << 16;
  return c.f;
}

__global__ void k_count(const int* __restrict__ idx, int* __restrict__ cnt, int E){
  int e = blockIdx.x*blockDim.x + threadIdx.x;
  if (e >= E) return;
  int2 rc = ((const int2*)idx)[e];
  atomicAdd(&cnt[rc.x], 1);
}

__global__ void k_blocksum(const int* __restrict__ rp, int* __restrict__ bsum, int N){
  int i = blockIdx.x*256 + threadIdx.x;
  int c = (i < N) ? rp[i] : 0;
  #pragma unroll
  for (int off = 1; off < 64; off <<= 1) c += __shfl_xor(c, off);
  __shared__ int s[4];
  if ((threadIdx.x & 63) == 0) s[threadIdx.x >> 6] = c;
  __syncthreads();
  if (threadIdx.x == 0) bsum[blockIdx.x] = s[0] + s[1] + s[2] + s[3];
}

__global__ void k_scanb(const int* __restrict__ bsum, int* __restrict__ boff,
                        int* __restrict__ rpN, int B){
  __shared__ int s[256];
  int t = threadIdx.x;
  int run = 0;
  for (int base = 0; base < B; base += 256){
    int c = (base + t < B) ? bsum[base + t] : 0;
    s[t] = c;
    __syncthreads();
    #pragma unroll
    for (int off = 1; off < 256; off <<= 1){
      int v = s[t];
      int u = (t >= off) ? s[t-off] : 0;
      __syncthreads();
      s[t] = v + u;
      __syncthreads();
    }
    if (base + t < B) boff[base + t] = run + s[t] - c;
    run += s[255];
    __syncthreads();
  }
  if (t == 0) rpN[0] = run;
}

__global__ void k_addoff(int* __restrict__ rp, int* __restrict__ cursor,
                         const int* __restrict__ boff, int N){
  __shared__ int s[256];
  int t = threadIdx.x;
  int i = blockIdx.x*256 + t;
  int c = (i < N) ? rp[i] : 0;
  s[t] = c;
  __syncthreads();
  #pragma unroll
  for (int off = 1; off < 256; off <<= 1){
    int v = s[t];
    int u = (t >= off) ? s[t-off] : 0;
    __syncthreads();
    s[t] = v + u;
    __syncthreads();
  }
  int excl = s[t] - c + boff[blockIdx.x];
  if (i < N){ rp[i] = excl; cursor[i] = excl; }
}

__global__ void k_scatter(const int* __restrict__ idx, const float* __restrict__ vals,
                          int* __restrict__ cursor, int* __restrict__ cols,
                          float* __restrict__ evals, int E){
  int e = blockIdx.x*blockDim.x + threadIdx.x;
  if (e >= E) return;
  int2 rc = ((const int2*)idx)[e];
  int p = atomicAdd(&cursor[rc.x], 1);
  cols[p] = rc.y;
  evals[p] = vals[e];
}

// out[r][:] = (1/clip(sum v,1)) * sum_e v_e * X[cols[e]][:]
__global__ void k_spmm(const int* __restrict__ rp, const int* __restrict__ cols,
                       const float* __restrict__ evals, const float* __restrict__ X,
                       float* __restrict__ out, int N){
  int r = blockIdx.x*8 + (threadIdx.x >> 5);
  int t = threadIdx.x & 31;
  if (r >= N) return;
  float4 acc = make_float4(0.f, 0.f, 0.f, 0.f);
  float vsum = 0.f;
  int e0 = rp[r], e1 = rp[r+1];
  int e = e0;
  for (; e + 1 < e1; e += 2){
    int c0 = cols[e],   c1 = cols[e+1];
    float v0 = evals[e], v1 = evals[e+1];
    float4 x0 = *(const float4*)&X[(size_t)c0*128 + t*4];
    float4 x1 = *(const float4*)&X[(size_t)c1*128 + t*4];
    vsum += v0 + v1;
    acc.x = fmaf(v0, x0.x, acc.x); acc.y = fmaf(v0, x0.y, acc.y);
    acc.z = fmaf(v0, x0.z, acc.z); acc.w = fmaf(v0, x0.w, acc.w);
    acc.x = fmaf(v1, x1.x, acc.x); acc.y = fmaf(v1, x1.y, acc.y);
    acc.z = fmaf(v1, x1.z, acc.z); acc.w = fmaf(v1, x1.w, acc.w);
  }
  if (e < e1){
    int c0 = cols[e]; float v0 = evals[e];
    float4 x0 = *(const float4*)&X[(size_t)c0*128 + t*4];
    vsum += v0;
    acc.x = fmaf(v0, x0.x, acc.x); acc.y = fmaf(v0, x0.y, acc.y);
    acc.z = fmaf(v0, x0.z, acc.z); acc.w = fmaf(v0, x0.w, acc.w);
  }
  float di = 1.0f / fmaxf(vsum, 1.0f);
  float4 o = make_float4(acc.x*di, acc.y*di, acc.z*di, acc.w*di);
  *(float4*)&out[(size_t)r*128 + t*4] = o;
}

// Pack W1,W2 (128x128 fp32) into MFMA B-fragment order, split hi/lo bf16.
__global__ void k_packW12(const float* __restrict__ W1, const float* __restrict__ W2,
                          short* __restrict__ Wh, short* __restrict__ Wl){
  int idx = blockIdx.x*256 + threadIdx.x;   // 2*16384
  int b = idx & 7, lane = (idx >> 3) & 63, kk = (idx >> 9) & 3, j = (idx >> 11) & 7;
  int m = idx >> 14;
  const float* W = m ? W2 : W1;
  int row = kk*32 + 8*(lane >> 4) + b;      // k index 0..127
  int col = j*16 + (lane & 15);
  float x = W[row*128 + col];
  short hb = f2bf(x);
  Wh[idx] = hb;
  Wl[idx] = f2bf(x - bf2f(hb));
}

// Pack Wd1 (256x128 fp32) into MFMA B-fragment order, bf16.
__global__ void k_packW(const float* __restrict__ Wd1, short* __restrict__ WdP){
  int idx = blockIdx.x*blockDim.x + threadIdx.x;   // 32768 total
  int b = idx & 7, lane = (idx >> 3) & 63, kk = (idx >> 9) & 7, j = (idx >> 12) & 7;
  int row = kk*32 + 8*(lane >> 4) + b;
  int col = j*16 + (lane & 15);
  WdP[idx] = f2bf(Wd1[row*128 + col]);
}

// Split-bf16 MFMA layer GEMM: out = maybe_relu(A @ W + bias), A:[M][128], W:128x128.
// 3-term split (hh + lh + hl) => ~2^-17 relative error (fp32-equivalent here).
template<bool RELU, bool EMIT>
__global__ __launch_bounds__(256)
void k_mgemm(const float* __restrict__ A, const short* __restrict__ Wh,
             const short* __restrict__ Wl, const float* __restrict__ bias,
             float* __restrict__ out, short* __restrict__ out_bf, int M)
{
  const int wave = threadIdx.x >> 6;
  const int lane = threadIdx.x & 63;
  const int l15 = lane & 15, lg = lane >> 4;
  const int wrow = blockIdx.x*64 + wave*16;
  int arow = wrow + l15; if (arow >= M) arow = M - 1;

  s16x8 ah[4], al[4];
  #pragma unroll
  for (int kk = 0; kk < 4; ++kk){
    const float* src = &A[(size_t)arow*128 + kk*32 + 8*lg];
    float4 x0 = *(const float4*)src;
    float4 x1 = *(const float4*)(src + 4);
    float xs[8] = {x0.x,x0.y,x0.z,x0.w,x1.x,x1.y,x1.z,x1.w};
    #pragma unroll
    for (int b = 0; b < 8; ++b){
      short hb = f2bf(xs[b]);
      ah[kk][b] = hb;
      al[kk][b] = f2bf(xs[b] - bf2f(hb));
    }
  }

  const s16x8* WH = (const s16x8*)Wh;
  const s16x8* WL = (const s16x8*)Wl;
  f32x4 acc[8];
  #pragma unroll
  for (int j = 0; j < 8; ++j) acc[j] = (f32x4){0.f,0.f,0.f,0.f};

  #pragma unroll
  for (int j = 0; j < 8; ++j){
    #pragma unroll
    for (int kk = 0; kk < 4; ++kk){
      s16x8 bh = WH[(j*4 + kk)*64 + lane];
      s16x8 bl = WL[(j*4 + kk)*64 + lane];
      acc[j] = __builtin_amdgcn_mfma_f32_16x16x32_bf16(ah[kk], bh, acc[j], 0, 0, 0);
      acc[j] = __builtin_amdgcn_mfma_f32_16x16x32_bf16(al[kk], bh, acc[j], 0, 0, 0);
      acc[j] = __builtin_amdgcn_mfma_f32_16x16x32_bf16(ah[kk], bl, acc[j], 0, 0, 0);
    }
  }

  #pragma unroll
  for (int j = 0; j < 8; ++j){
    int col = j*16 + l15;
    float bb = bias[col];
    #pragma unroll
    for (int r = 0; r < 4; ++r){
      int row = wrow + 4*lg + r;
      if (row < M){
        float v = acc[j][r] + bb;
        if (RELU) v = fmaxf(v, 0.f);
        out[(size_t)row*128 + col] = v;
        if (EMIT) out_bf[(size_t)row*128 + col] = f2bf(v);
      }
    }
  }
}

// Decoder: out[p] = relu(concat(h2[u],h2[v]) @ Wd1 + bd1) @ Wd2 + bd2
__global__ __launch_bounds__(256)
void k_decode(const short* __restrict__ h2b, const short* __restrict__ WdP,
              const float* __restrict__ bd1, const float* __restrict__ wd2,
              const float* __restrict__ bd2, const int* __restrict__ iu,
              const int* __restrict__ iv, float* __restrict__ out, int P)
{
  const int wave = threadIdx.x >> 6;
  const int lane = threadIdx.x & 63;
  const int l15 = lane & 15, lg = lane >> 4;
  const int wbase = blockIdx.x*128 + wave*32;

  int ra0 = wbase + l15;      if (ra0 >= P) ra0 = P - 1;
  int ra1 = wbase + 16 + l15; if (ra1 >= P) ra1 = P - 1;
  int u0 = iu[ra0], v0 = iv[ra0];
  int u1 = iu[ra1], v1 = iv[ra1];

  s16x8 a0[8], a1[8];
  #pragma unroll
  for (int kk = 0; kk < 8; ++kk){
    int kg = kk*32 + 8*lg;
    const short* s0 = (kg < 128) ? h2b + (size_t)u0*128 + kg
                                 : h2b + (size_t)v0*128 + (kg - 128);
    const short* s1 = (kg < 128) ? h2b + (size_t)u1*128 + kg
                                 : h2b + (size_t)v1*128 + (kg - 128);
    a0[kk] = *(const s16x8*)s0;
    a1[kk] = *(const s16x8*)s1;
  }

  const s16x8* Wp = (const s16x8*)WdP;
  f32x4 acc0[8], acc1[8];
  #pragma unroll
  for (int j = 0; j < 8; ++j){
    acc0[j] = (f32x4){0.f,0.f,0.f,0.f};
    acc1[j] = (f32x4){0.f,0.f,0.f,0.f};
  }

  #pragma unroll
  for (int j = 0; j < 8; ++j){
    #pragma unroll
    for (int kk = 0; kk < 8; ++kk){
      s16x8 b = Wp[(j*8 + kk)*64 + lane];
      acc0[j] = __builtin_amdgcn_mfma_f32_16x16x32_bf16(a0[kk], b, acc0[j], 0, 0, 0);
      acc1[j] = __builtin_amdgcn_mfma_f32_16x16x32_bf16(a1[kk], b, acc1[j], 0, 0, 0);
    }
  }

  float part0[4] = {0,0,0,0}, part1[4] = {0,0,0,0};
  #pragma unroll
  for (int j = 0; j < 8; ++j){
    int col = j*16 + l15;
    float bb = bd1[col], ww = wd2[col];
    #pragma unroll
    for (int r = 0; r < 4; ++r){
      part0[r] = fmaf(fmaxf(acc0[j][r] + bb, 0.f), ww, part0[r]);
      part1[r] = fmaf(fmaxf(acc1[j][r] + bb, 0.f), ww, part1[r]);
    }
  }
  #pragma unroll
  for (int off = 1; off < 16; off <<= 1){
    #pragma unroll
    for (int r = 0; r < 4; ++r){
      part0[r] += __shfl_xor(part0[r], off);
      part1[r] += __shfl_xor(part1[r], off);
    }
  }
  if (l15 == 0){
    float b2v = bd2[0];
    int m0 = wbase + 4*lg, m1 = wbase + 16 + 4*lg;
    #pragma unroll
    for (int r = 0; r < 4; ++r){
      if (m0 + r < P) out[m0 + r] = part0[r] + b2v;
      if (m1 + r < P) out[m1 + r] = part1[r] + b2v;
    }
  }
}

extern "C" void kernel_launch(void* const* d_in, const int* in_sizes, int n_in,
                              void* d_out, int out_size, void* d_ws, size_t ws_size,
                              hipStream_t stream){
  const int*   adj   = (const int*)  d_in[0];
  const float* av    = (const float*)d_in[1];
  const float* h     = (const float*)d_in[3];
  const int*   pos_u = (const int*)  d_in[4];
  const int*   pos_v = (const int*)  d_in[5];
  const int*   neg_u = (const int*)  d_in[6];
  const int*   neg_v = (const int*)  d_in[7];
  const float* W1    = (const float*)d_in[8];
  const float* b1    = (const float*)d_in[9];
  const float* W2    = (const float*)d_in[10];
  const float* b2    = (const float*)d_in[11];
  const float* Wd1   = (const float*)d_in[12];
  const float* bd1   = (const float*)d_in[13];
  const float* Wd2   = (const float*)d_in[14];
  const float* bd2   = (const float*)d_in[15];

  const int E = in_sizes[0] / 2;
  const int N = in_sizes[3] / 128;
  const int P = in_sizes[4];
  const int NB = (N + 255) / 256;

  auto al = [](size_t x){ return (x + 255) & ~(size_t)255; };
  char* base = (char*)d_ws;
  size_t off = 0;
  int*   rp     = (int*)(base + off);   off = al(off + (size_t)(N+1)*4);
  int*   cursor = (int*)(base + off);   off = al(off + (size_t)N*4);
  int*   bsum   = (int*)(base + off);   off = al(off + (size_t)NB*4);
  int*   boff   = (int*)(base + off);   off = al(off + (size_t)NB*4);
  int*   cols   = (int*)(base + off);   off = al(off + (size_t)E*4);
  float* evals  = (float*)(base + off); off = al(off + (size_t)E*4);
  short* W12h   = (short*)(base + off); off = al(off + (size_t)32768*2);
  short* W12l   = (short*)(base + off); off = al(off + (size_t)32768*2);
  short* WdP    = (short*)(base + off); off = al(off + (size_t)32768*2);  // DEDICATED (round-5 fix)
  size_t h1_off = off;
  float* h1     = (float*)(base + off); off = al(off + (size_t)N*128*4);
  // h1 region reused for bf16 copy of h2 AFTER h1 is dead:
  short* h2b    = (short*)(base + h1_off);

  float* scores_pos = (float*)d_out;
  float* scores_neg = scores_pos + P;
  float* h2         = scores_neg + P;   // spmm accumulator + final fp32 output

  hipMemsetAsync(rp, 0, (size_t)(N+1)*4, stream);

  k_count   <<<(E+255)/256, 256, 0, stream>>>(adj, rp, E);
  k_blocksum<<<NB, 256, 0, stream>>>(rp, bsum, N);
  k_scanb   <<<1, 256, 0, stream>>>(bsum, boff, rp + N, NB);
  k_addoff  <<<NB, 256, 0, stream>>>(rp, cursor, boff, N);
  k_scatter <<<(E+255)/256, 256, 0, stream>>>(adj, av, cursor, cols, evals, E);
  k_packW12 <<<128, 256, 0, stream>>>(W1, W2, W12h, W12l);
  k_packW   <<<128, 256, 0, stream>>>(Wd1, WdP);

  // layer 1
  k_spmm<<<(N+7)/8, 256, 0, stream>>>(rp, cols, evals, h, h2, N);
  k_mgemm<true , false><<<(N+63)/64, 256, 0, stream>>>(h2, W12h, W12l, b1, h1, nullptr, N);

  // layer 2 (h1 dead after spmm; mgemm in-place on h2, emits bf16 copy into old-h1)
  k_spmm<<<(N+7)/8, 256, 0, stream>>>(rp, cols, evals, h1, h2, N);
  k_mgemm<false, true ><<<(N+63)/64, 256, 0, stream>>>(h2, W12h + 16384, W12l + 16384, b2, h2, h2b, N);

  // decoder
  k_decode<<<(P+127)/128, 256, 0, stream>>>(h2b, WdP, bd1, Wd2, bd2, pos_u, pos_v, scores_pos, P);
  k_decode<<<(P+127)/128, 256, 0, stream>>>(h2b, WdP, bd1, Wd2, bd2, neg_u, neg_v, scores_neg, P);
}

// Round 7
// 403.054 us; speedup vs baseline: 2.3745x; 1.0113x over previous
//
#include <hip/hip_runtime.h>

// SparseGraphSAGE: CSR build (count -> hierarchical scan -> scatter) ->
// spmm(fused deg, ILP-4) -> split-bf16 MFMA gemm(relu) -> spmm -> MFMA gemm(+bf16 emit)
// -> bf16-MFMA gathered decoder (pos+neg fused) with fused final dot.

typedef float  f32x4 __attribute__((ext_vector_type(4)));
typedef short  s16x8 __attribute__((ext_vector_type(8)));
typedef short  s16x4 __attribute__((ext_vector_type(4)));

__device__ inline short f2bf(float f){
  union { float f; unsigned u; } x; x.f = f;
  unsigned u = x.u;
  return (short)((u + 0x7FFFu + ((u >> 16) & 1u)) >> 16);   // RNE
}
__device__ inline float bf2f(short h){
  union { unsigned u; float f; } c; c.u = ((unsigned)(unsigned short)h) << 16;
  return c.f;
}

__global__ void k_count(const int* __restrict__ idx, int* __restrict__ cnt, int E){
  int e = blockIdx.x*blockDim.x + threadIdx.x;
  if (e >= E) return;
  int2 rc = ((const int2*)idx)[e];
  atomicAdd(&cnt[rc.x], 1);
}

__global__ void k_blocksum(const int* __restrict__ rp, int* __restrict__ bsum, int N){
  int i = blockIdx.x*256 + threadIdx.x;
  int c = (i < N) ? rp[i] : 0;
  #pragma unroll
  for (int off = 1; off < 64; off <<= 1) c += __shfl_xor(c, off);
  __shared__ int s[4];
  if ((threadIdx.x & 63) == 0) s[threadIdx.x >> 6] = c;
  __syncthreads();
  if (threadIdx.x == 0) bsum[blockIdx.x] = s[0] + s[1] + s[2] + s[3];
}

__global__ void k_scanb(const int* __restrict__ bsum, int* __restrict__ boff,
                        int* __restrict__ rpN, int B){
  __shared__ int s[256];
  int t = threadIdx.x;
  int run = 0;
  for (int base = 0; base < B; base += 256){
    int c = (base + t < B) ? bsum[base + t] : 0;
    s[t] = c;
    __syncthreads();
    #pragma unroll
    for (int off = 1; off < 256; off <<= 1){
      int v = s[t];
      int u = (t >= off) ? s[t-off] : 0;
      __syncthreads();
      s[t] = v + u;
      __syncthreads();
    }
    if (base + t < B) boff[base + t] = run + s[t] - c;
    run += s[255];
    __syncthreads();
  }
  if (t == 0) rpN[0] = run;
}

__global__ void k_addoff(int* __restrict__ rp, int* __restrict__ cursor,
                         const int* __restrict__ boff, int N){
  __shared__ int s[256];
  int t = threadIdx.x;
  int i = blockIdx.x*256 + t;
  int c = (i < N) ? rp[i] : 0;
  s[t] = c;
  __syncthreads();
  #pragma unroll
  for (int off = 1; off < 256; off <<= 1){
    int v = s[t];
    int u = (t >= off) ? s[t-off] : 0;
    __syncthreads();
    s[t] = v + u;
    __syncthreads();
  }
  int excl = s[t] - c + boff[blockIdx.x];
  if (i < N){ rp[i] = excl; cursor[i] = excl; }
}

__global__ void k_scatter(const int* __restrict__ idx, const float* __restrict__ vals,
                          int* __restrict__ cursor, int* __restrict__ cols,
                          float* __restrict__ evals, int E){
  int e = blockIdx.x*blockDim.x + threadIdx.x;
  if (e >= E) return;
  int2 rc = ((const int2*)idx)[e];
  int p = atomicAdd(&cursor[rc.x], 1);
  cols[p] = rc.y;
  evals[p] = vals[e];
}

// out[r][:] = (1/clip(sum v,1)) * sum_e v_e * X[cols[e]][:]
// 8 rows/block, 32 lanes x float4 per row, 4-edge unroll (4 gathers in flight).
__global__ void k_spmm(const int* __restrict__ rp, const int* __restrict__ cols,
                       const float* __restrict__ evals, const float* __restrict__ X,
                       float* __restrict__ out, int N){
  int r = blockIdx.x*8 + (threadIdx.x >> 5);
  int t = threadIdx.x & 31;
  if (r >= N) return;
  f32x4 acc0 = {0.f,0.f,0.f,0.f}, acc1 = {0.f,0.f,0.f,0.f};
  float vs0 = 0.f, vs1 = 0.f;
  int e0 = rp[r], e1 = rp[r+1];
  int e = e0;
  for (; e + 3 < e1; e += 4){
    int c0 = cols[e],  c1 = cols[e+1], c2 = cols[e+2], c3 = cols[e+3];
    float v0 = evals[e],   v1 = evals[e+1];
    float v2 = evals[e+2], v3 = evals[e+3];
    f32x4 x0 = *(const f32x4*)&X[(size_t)c0*128 + t*4];
    f32x4 x1 = *(const f32x4*)&X[(size_t)c1*128 + t*4];
    f32x4 x2 = *(const f32x4*)&X[(size_t)c2*128 + t*4];
    f32x4 x3 = *(const f32x4*)&X[(size_t)c3*128 + t*4];
    acc0 += v0 * x0; acc1 += v1 * x1;
    acc0 += v2 * x2; acc1 += v3 * x3;
    vs0 += v0 + v2;  vs1 += v1 + v3;
  }
  for (; e < e1; ++e){
    int c0 = cols[e]; float v0 = evals[e];
    f32x4 x0 = *(const f32x4*)&X[(size_t)c0*128 + t*4];
    acc0 += v0 * x0;
    vs0 += v0;
  }
  f32x4 acc = acc0 + acc1;
  float di = 1.0f / fmaxf(vs0 + vs1, 1.0f);
  acc *= di;
  *(f32x4*)&out[(size_t)r*128 + t*4] = acc;
}

// Fused weight packing:
// idx < 32768: W1/W2 -> MFMA B-fragment order, split hi/lo bf16.
// idx >= 32768: Wd1 (256x128) -> MFMA B-fragment order, bf16.
__global__ void k_pack(const float* __restrict__ W1, const float* __restrict__ W2,
                       const float* __restrict__ Wd1,
                       short* __restrict__ Wh, short* __restrict__ Wl,
                       short* __restrict__ WdP){
  int gid = blockIdx.x*256 + threadIdx.x;     // 65536 total
  if (gid < 32768){
    int idx = gid;
    int b = idx & 7, lane = (idx >> 3) & 63, kk = (idx >> 9) & 3, j = (idx >> 11) & 7;
    int m = idx >> 14;
    const float* W = m ? W2 : W1;
    int row = kk*32 + 8*(lane >> 4) + b;      // k index 0..127
    int col = j*16 + (lane & 15);
    float x = W[row*128 + col];
    short hb = f2bf(x);
    Wh[idx] = hb;
    Wl[idx] = f2bf(x - bf2f(hb));
  } else {
    int idx = gid - 32768;
    int b = idx & 7, lane = (idx >> 3) & 63, kk = (idx >> 9) & 7, j = (idx >> 12) & 7;
    int row = kk*32 + 8*(lane >> 4) + b;
    int col = j*16 + (lane & 15);
    WdP[idx] = f2bf(Wd1[row*128 + col]);
  }
}

// Split-bf16 MFMA layer GEMM: out = maybe_relu(A @ W + bias), A:[M][128], W:128x128.
// 3-term split (hh + lh + hl) => ~2^-17 relative error (fp32-equivalent here).
template<bool RELU, bool EMIT>
__global__ __launch_bounds__(256)
void k_mgemm(const float* __restrict__ A, const short* __restrict__ Wh,
             const short* __restrict__ Wl, const float* __restrict__ bias,
             float* __restrict__ out, short* __restrict__ out_bf, int M)
{
  const int wave = threadIdx.x >> 6;
  const int lane = threadIdx.x & 63;
  const int l15 = lane & 15, lg = lane >> 4;
  const int wrow = blockIdx.x*64 + wave*16;
  int arow = wrow + l15; if (arow >= M) arow = M - 1;

  s16x8 ah[4], al[4];
  #pragma unroll
  for (int kk = 0; kk < 4; ++kk){
    const float* src = &A[(size_t)arow*128 + kk*32 + 8*lg];
    float4 x0 = *(const float4*)src;
    float4 x1 = *(const float4*)(src + 4);
    float xs[8] = {x0.x,x0.y,x0.z,x0.w,x1.x,x1.y,x1.z,x1.w};
    #pragma unroll
    for (int b = 0; b < 8; ++b){
      short hb = f2bf(xs[b]);
      ah[kk][b] = hb;
      al[kk][b] = f2bf(xs[b] - bf2f(hb));
    }
  }

  const s16x8* WH = (const s16x8*)Wh;
  const s16x8* WL = (const s16x8*)Wl;
  f32x4 acc[8];
  #pragma unroll
  for (int j = 0; j < 8; ++j) acc[j] = (f32x4){0.f,0.f,0.f,0.f};

  #pragma unroll
  for (int j = 0; j < 8; ++j){
    #pragma unroll
    for (int kk = 0; kk < 4; ++kk){
      s16x8 bh = WH[(j*4 + kk)*64 + lane];
      s16x8 bl = WL[(j*4 + kk)*64 + lane];
      acc[j] = __builtin_amdgcn_mfma_f32_16x16x32_bf16(ah[kk], bh, acc[j], 0, 0, 0);
      acc[j] = __builtin_amdgcn_mfma_f32_16x16x32_bf16(al[kk], bh, acc[j], 0, 0, 0);
      acc[j] = __builtin_amdgcn_mfma_f32_16x16x32_bf16(ah[kk], bl, acc[j], 0, 0, 0);
    }
  }

  #pragma unroll
  for (int j = 0; j < 8; ++j){
    int col = j*16 + l15;
    float bb = bias[col];
    #pragma unroll
    for (int r = 0; r < 4; ++r){
      int row = wrow + 4*lg + r;
      if (row < M){
        float v = acc[j][r] + bb;
        if (RELU) v = fmaxf(v, 0.f);
        out[(size_t)row*128 + col] = v;
        if (EMIT) out_bf[(size_t)row*128 + col] = f2bf(v);
      }
    }
  }
}

// Decoder (pos+neg fused via blockIdx.y):
// out[p] = relu(concat(h2[u],h2[v]) @ Wd1 + bd1) @ Wd2 + bd2
__global__ __launch_bounds__(256)
void k_decode(const short* __restrict__ h2b, const short* __restrict__ WdP,
              const float* __restrict__ bd1, const float* __restrict__ wd2,
              const float* __restrict__ bd2,
              const int* __restrict__ pos_u, const int* __restrict__ pos_v,
              const int* __restrict__ neg_u, const int* __restrict__ neg_v,
              float* __restrict__ out_pos, float* __restrict__ out_neg, int P)
{
  const int which = blockIdx.y;
  const int* iu = which ? neg_u : pos_u;
  const int* iv = which ? neg_v : pos_v;
  float* out = which ? out_neg : out_pos;

  const int wave = threadIdx.x >> 6;
  const int lane = threadIdx.x & 63;
  const int l15 = lane & 15, lg = lane >> 4;
  const int wbase = blockIdx.x*128 + wave*32;

  int ra0 = wbase + l15;      if (ra0 >= P) ra0 = P - 1;
  int ra1 = wbase + 16 + l15; if (ra1 >= P) ra1 = P - 1;
  int u0 = iu[ra0], v0 = iv[ra0];
  int u1 = iu[ra1], v1 = iv[ra1];

  s16x8 a0[8], a1[8];
  #pragma unroll
  for (int kk = 0; kk < 8; ++kk){
    int kg = kk*32 + 8*lg;
    const short* s0 = (kg < 128) ? h2b + (size_t)u0*128 + kg
                                 : h2b + (size_t)v0*128 + (kg - 128);
    const short* s1 = (kg < 128) ? h2b + (size_t)u1*128 + kg
                                 : h2b + (size_t)v1*128 + (kg - 128);
    a0[kk] = *(const s16x8*)s0;
    a1[kk] = *(const s16x8*)s1;
  }

  const s16x8* Wp = (const s16x8*)WdP;
  f32x4 acc0[8], acc1[8];
  #pragma unroll
  for (int j = 0; j < 8; ++j){
    acc0[j] = (f32x4){0.f,0.f,0.f,0.f};
    acc1[j] = (f32x4){0.f,0.f,0.f,0.f};
  }

  #pragma unroll
  for (int j = 0; j < 8; ++j){
    #pragma unroll
    for (int kk = 0; kk < 8; ++kk){
      s16x8 b = Wp[(j*8 + kk)*64 + lane];
      acc0[j] = __builtin_amdgcn_mfma_f32_16x16x32_bf16(a0[kk], b, acc0[j], 0, 0, 0);
      acc1[j] = __builtin_amdgcn_mfma_f32_16x16x32_bf16(a1[kk], b, acc1[j], 0, 0, 0);
    }
  }

  float part0[4] = {0,0,0,0}, part1[4] = {0,0,0,0};
  #pragma unroll
  for (int j = 0; j < 8; ++j){
    int col = j*16 + l15;
    float bb = bd1[col], ww = wd2[col];
    #pragma unroll
    for (int r = 0; r < 4; ++r){
      part0[r] = fmaf(fmaxf(acc0[j][r] + bb, 0.f), ww, part0[r]);
      part1[r] = fmaf(fmaxf(acc1[j][r] + bb, 0.f), ww, part1[r]);
    }
  }
  #pragma unroll
  for (int off = 1; off < 16; off <<= 1){
    #pragma unroll
    for (int r = 0; r < 4; ++r){
      part0[r] += __shfl_xor(part0[r], off);
      part1[r] += __shfl_xor(part1[r], off);
    }
  }
  if (l15 == 0){
    float b2v = bd2[0];
    int m0 = wbase + 4*lg, m1 = wbase + 16 + 4*lg;
    #pragma unroll
    for (int r = 0; r < 4; ++r){
      if (m0 + r < P) out[m0 + r] = part0[r] + b2v;
      if (m1 + r < P) out[m1 + r] = part1[r] + b2v;
    }
  }
}

extern "C" void kernel_launch(void* const* d_in, const int* in_sizes, int n_in,
                              void* d_out, int out_size, void* d_ws, size_t ws_size,
                              hipStream_t stream){
  const int*   adj   = (const int*)  d_in[0];
  const float* av    = (const float*)d_in[1];
  const float* h     = (const float*)d_in[3];
  const int*   pos_u = (const int*)  d_in[4];
  const int*   pos_v = (const int*)  d_in[5];
  const int*   neg_u = (const int*)  d_in[6];
  const int*   neg_v = (const int*)  d_in[7];
  const float* W1    = (const float*)d_in[8];
  const float* b1    = (const float*)d_in[9];
  const float* W2    = (const float*)d_in[10];
  const float* b2    = (const float*)d_in[11];
  const float* Wd1   = (const float*)d_in[12];
  const float* bd1   = (const float*)d_in[13];
  const float* Wd2   = (const float*)d_in[14];
  const float* bd2   = (const float*)d_in[15];

  const int E = in_sizes[0] / 2;
  const int N = in_sizes[3] / 128;
  const int P = in_sizes[4];
  const int NB = (N + 255) / 256;

  auto al = [](size_t x){ return (x + 255) & ~(size_t)255; };
  char* base = (char*)d_ws;
  size_t off = 0;
  int*   rp     = (int*)(base + off);   off = al(off + (size_t)(N+1)*4);
  int*   cursor = (int*)(base + off);   off = al(off + (size_t)N*4);
  int*   bsum   = (int*)(base + off);   off = al(off + (size_t)NB*4);
  int*   boff   = (int*)(base + off);   off = al(off + (size_t)NB*4);
  int*   cols   = (int*)(base + off);   off = al(off + (size_t)E*4);
  float* evals  = (float*)(base + off); off = al(off + (size_t)E*4);
  short* W12h   = (short*)(base + off); off = al(off + (size_t)32768*2);
  short* W12l   = (short*)(base + off); off = al(off + (size_t)32768*2);
  short* WdP    = (short*)(base + off); off = al(off + (size_t)32768*2);  // dedicated
  size_t h1_off = off;
  float* h1     = (float*)(base + off); off = al(off + (size_t)N*128*4);
  // h1 region reused for bf16 copy of h2 AFTER h1 is dead:
  short* h2b    = (short*)(base + h1_off);

  float* scores_pos = (float*)d_out;
  float* scores_neg = scores_pos + P;
  float* h2         = scores_neg + P;   // spmm accumulator + final fp32 output

  hipMemsetAsync(rp, 0, (size_t)(N+1)*4, stream);

  k_count   <<<(E+255)/256, 256, 0, stream>>>(adj, rp, E);
  k_blocksum<<<NB, 256, 0, stream>>>(rp, bsum, N);
  k_scanb   <<<1, 256, 0, stream>>>(bsum, boff, rp + N, NB);
  k_addoff  <<<NB, 256, 0, stream>>>(rp, cursor, boff, N);
  k_scatter <<<(E+255)/256, 256, 0, stream>>>(adj, av, cursor, cols, evals, E);
  k_pack    <<<256, 256, 0, stream>>>(W1, W2, Wd1, W12h, W12l, WdP);

  // layer 1
  k_spmm<<<(N+7)/8, 256, 0, stream>>>(rp, cols, evals, h, h2, N);
  k_mgemm<true , false><<<(N+63)/64, 256, 0, stream>>>(h2, W12h, W12l, b1, h1, nullptr, N);

  // layer 2 (h1 dead after spmm; mgemm in-place on h2, emits bf16 copy into old-h1)
  k_spmm<<<(N+7)/8, 256, 0, stream>>>(rp, cols, evals, h1, h2, N);
  k_mgemm<false, true ><<<(N+63)/64, 256, 0, stream>>>(h2, W12h + 16384, W12l + 16384, b2, h2, h2b, N);

  // decoder (pos & neg in one dispatch)
  dim3 dgrid((P+127)/128, 2);
  k_decode<<<dgrid, 256, 0, stream>>>(h2b, WdP, bd1, Wd2, bd2,
                                      pos_u, pos_v, neg_u, neg_v,
                                      scores_pos, scores_neg, P);
}

// Round 8
// 347.248 us; speedup vs baseline: 2.7560x; 1.1607x over previous
//
#include <hip/hip_runtime.h>

// SparseGraphSAGE: CSR build (count -> hierarchical scan -> scatter int2) ->
// bf16-gather spmm (fused deg) -> split-bf16 MFMA gemm(relu, emit bf16) ->
// bf16-gather spmm -> MFMA gemm(fp32 + bf16 emit) -> bf16-MFMA fused decoder.

typedef float  f32x4 __attribute__((ext_vector_type(4)));
typedef short  s16x8 __attribute__((ext_vector_type(8)));
typedef short  s16x4 __attribute__((ext_vector_type(4)));

__device__ inline short f2bf(float f){
  union { float f; unsigned u; } x; x.f = f;
  unsigned u = x.u;
  return (short)((u + 0x7FFFu + ((u >> 16) & 1u)) >> 16);   // RNE
}
__device__ inline float bf2f(short h){
  union { unsigned u; float f; } c; c.u = ((unsigned)(unsigned short)h) << 16;
  return c.f;
}

__global__ void k_count(const int* __restrict__ idx, int* __restrict__ cnt, int E){
  int e = blockIdx.x*blockDim.x + threadIdx.x;
  if (e >= E) return;
  int2 rc = ((const int2*)idx)[e];
  atomicAdd(&cnt[rc.x], 1);
}

__global__ void k_blocksum(const int* __restrict__ rp, int* __restrict__ bsum, int N){
  int i = blockIdx.x*256 + threadIdx.x;
  int c = (i < N) ? rp[i] : 0;
  #pragma unroll
  for (int off = 1; off < 64; off <<= 1) c += __shfl_xor(c, off);
  __shared__ int s[4];
  if ((threadIdx.x & 63) == 0) s[threadIdx.x >> 6] = c;
  __syncthreads();
  if (threadIdx.x == 0) bsum[blockIdx.x] = s[0] + s[1] + s[2] + s[3];
}

__global__ void k_scanb(const int* __restrict__ bsum, int* __restrict__ boff,
                        int* __restrict__ rpN, int B){
  __shared__ int s[256];
  int t = threadIdx.x;
  int run = 0;
  for (int base = 0; base < B; base += 256){
    int c = (base + t < B) ? bsum[base + t] : 0;
    s[t] = c;
    __syncthreads();
    #pragma unroll
    for (int off = 1; off < 256; off <<= 1){
      int v = s[t];
      int u = (t >= off) ? s[t-off] : 0;
      __syncthreads();
      s[t] = v + u;
      __syncthreads();
    }
    if (base + t < B) boff[base + t] = run + s[t] - c;
    run += s[255];
    __syncthreads();
  }
  if (t == 0) rpN[0] = run;
}

__global__ void k_addoff(int* __restrict__ rp, int* __restrict__ cursor,
                         const int* __restrict__ boff, int N){
  __shared__ int s[256];
  int t = threadIdx.x;
  int i = blockIdx.x*256 + t;
  int c = (i < N) ? rp[i] : 0;
  s[t] = c;
  __syncthreads();
  #pragma unroll
  for (int off = 1; off < 256; off <<= 1){
    int v = s[t];
    int u = (t >= off) ? s[t-off] : 0;
    __syncthreads();
    s[t] = v + u;
    __syncthreads();
  }
  int excl = s[t] - c + boff[blockIdx.x];
  if (i < N){ rp[i] = excl; cursor[i] = excl; }
}

// scatter fused (col, val) pairs: one 8B store per edge
__global__ void k_scatter(const int* __restrict__ idx, const float* __restrict__ vals,
                          int* __restrict__ cursor, int2* __restrict__ ce, int E){
  int e = blockIdx.x*blockDim.x + threadIdx.x;
  if (e >= E) return;
  int2 rc = ((const int2*)idx)[e];
  int p = atomicAdd(&cursor[rc.x], 1);
  ce[p] = make_int2(rc.y, __float_as_int(vals[e]));
}

// prep: h -> bf16 copy; pack W1/W2 split hi/lo; pack Wd1 bf16. One dispatch.
__global__ void k_prep(const float* __restrict__ h, const float* __restrict__ W1,
                       const float* __restrict__ W2, const float* __restrict__ Wd1,
                       short* __restrict__ hb, short* __restrict__ Wh,
                       short* __restrict__ Wl, short* __restrict__ WdP, int n4){
  int gid = blockIdx.x*256 + threadIdx.x;
  if (gid < n4){
    float4 v = ((const float4*)h)[gid];
    s16x4 o; o[0]=f2bf(v.x); o[1]=f2bf(v.y); o[2]=f2bf(v.z); o[3]=f2bf(v.w);
    *(s16x4*)&hb[(size_t)gid*4] = o;
  } else if (gid < n4 + 32768){
    int idx = gid - n4;
    int b = idx & 7, lane = (idx >> 3) & 63, kk = (idx >> 9) & 3, j = (idx >> 11) & 7;
    int m = idx >> 14;
    const float* W = m ? W2 : W1;
    int row = kk*32 + 8*(lane >> 4) + b;
    int col = j*16 + (lane & 15);
    float x = W[row*128 + col];
    short hbit = f2bf(x);
    Wh[idx] = hbit;
    Wl[idx] = f2bf(x - bf2f(hbit));
  } else if (gid < n4 + 65536){
    int idx = gid - n4 - 32768;
    int b = idx & 7, lane = (idx >> 3) & 63, kk = (idx >> 9) & 7, j = (idx >> 12) & 7;
    int row = kk*32 + 8*(lane >> 4) + b;
    int col = j*16 + (lane & 15);
    WdP[idx] = f2bf(Wd1[row*128 + col]);
  }
}

// out[r][:] = (1/clip(sum v,1)) * sum_e v_e * Xb[col_e][:]   (bf16 gather, fp32 accum)
// 16 rows/block, 16 lanes x 8 bf16 (16B) per row, 4-edge unroll.
__global__ void k_spmm(const int* __restrict__ rp, const int2* __restrict__ ce,
                       const short* __restrict__ Xb, float* __restrict__ out, int N){
  int r = blockIdx.x*16 + (threadIdx.x >> 4);
  int t = threadIdx.x & 15;
  if (r >= N) return;
  f32x4 a0 = {0.f,0.f,0.f,0.f}, a1 = {0.f,0.f,0.f,0.f};
  float vs0 = 0.f, vs1 = 0.f;
  int e0 = rp[r], e1 = rp[r+1];
  int e = e0;
  for (; e + 3 < e1; e += 4){
    int2 p0 = ce[e], p1 = ce[e+1], p2 = ce[e+2], p3 = ce[e+3];
    s16x8 x0 = *(const s16x8*)&Xb[(size_t)p0.x*128 + t*8];
    s16x8 x1 = *(const s16x8*)&Xb[(size_t)p1.x*128 + t*8];
    s16x8 x2 = *(const s16x8*)&Xb[(size_t)p2.x*128 + t*8];
    s16x8 x3 = *(const s16x8*)&Xb[(size_t)p3.x*128 + t*8];
    float v0 = __int_as_float(p0.y), v1 = __int_as_float(p1.y);
    float v2 = __int_as_float(p2.y), v3 = __int_as_float(p3.y);
    #pragma unroll
    for (int b = 0; b < 4; ++b){
      a0[b] = fmaf(v0, bf2f(x0[b]), a0[b]);   a1[b] = fmaf(v0, bf2f(x0[b+4]), a1[b]);
      a0[b] = fmaf(v1, bf2f(x1[b]), a0[b]);   a1[b] = fmaf(v1, bf2f(x1[b+4]), a1[b]);
      a0[b] = fmaf(v2, bf2f(x2[b]), a0[b]);   a1[b] = fmaf(v2, bf2f(x2[b+4]), a1[b]);
      a0[b] = fmaf(v3, bf2f(x3[b]), a0[b]);   a1[b] = fmaf(v3, bf2f(x3[b+4]), a1[b]);
    }
    vs0 += v0 + v2; vs1 += v1 + v3;
  }
  for (; e < e1; ++e){
    int2 p0 = ce[e];
    s16x8 x0 = *(const s16x8*)&Xb[(size_t)p0.x*128 + t*8];
    float v0 = __int_as_float(p0.y);
    #pragma unroll
    for (int b = 0; b < 4; ++b){
      a0[b] = fmaf(v0, bf2f(x0[b]), a0[b]);
      a1[b] = fmaf(v0, bf2f(x0[b+4]), a1[b]);
    }
    vs0 += v0;
  }
  float di = 1.0f / fmaxf(vs0 + vs1, 1.0f);
  a0 *= di; a1 *= di;
  *(f32x4*)&out[(size_t)r*128 + t*8]     = a0;
  *(f32x4*)&out[(size_t)r*128 + t*8 + 4] = a1;
}

// Split-bf16 MFMA layer GEMM: out = maybe_relu(A @ W + bias), A:[M][128] fp32.
// 3-term split (hh + lh + hl) => ~2^-17 relative error.
template<bool RELU, bool EMIT_F32, bool EMIT_BF16>
__global__ __launch_bounds__(256)
void k_mgemm(const float* __restrict__ A, const short* __restrict__ Wh,
             const short* __restrict__ Wl, const float* __restrict__ bias,
             float* __restrict__ out, short* __restrict__ out_bf, int M)
{
  const int wave = threadIdx.x >> 6;
  const int lane = threadIdx.x & 63;
  const int l15 = lane & 15, lg = lane >> 4;
  const int wrow = blockIdx.x*64 + wave*16;
  int arow = wrow + l15; if (arow >= M) arow = M - 1;

  s16x8 ah[4], al[4];
  #pragma unroll
  for (int kk = 0; kk < 4; ++kk){
    const float* src = &A[(size_t)arow*128 + kk*32 + 8*lg];
    float4 x0 = *(const float4*)src;
    float4 x1 = *(const float4*)(src + 4);
    float xs[8] = {x0.x,x0.y,x0.z,x0.w,x1.x,x1.y,x1.z,x1.w};
    #pragma unroll
    for (int b = 0; b < 8; ++b){
      short hb = f2bf(xs[b]);
      ah[kk][b] = hb;
      al[kk][b] = f2bf(xs[b] - bf2f(hb));
    }
  }

  const s16x8* WH = (const s16x8*)Wh;
  const s16x8* WL = (const s16x8*)Wl;
  f32x4 acc[8];
  #pragma unroll
  for (int j = 0; j < 8; ++j) acc[j] = (f32x4){0.f,0.f,0.f,0.f};

  #pragma unroll
  for (int j = 0; j < 8; ++j){
    #pragma unroll
    for (int kk = 0; kk < 4; ++kk){
      s16x8 bh = WH[(j*4 + kk)*64 + lane];
      s16x8 bl = WL[(j*4 + kk)*64 + lane];
      acc[j] = __builtin_amdgcn_mfma_f32_16x16x32_bf16(ah[kk], bh, acc[j], 0, 0, 0);
      acc[j] = __builtin_amdgcn_mfma_f32_16x16x32_bf16(al[kk], bh, acc[j], 0, 0, 0);
      acc[j] = __builtin_amdgcn_mfma_f32_16x16x32_bf16(ah[kk], bl, acc[j], 0, 0, 0);
    }
  }

  #pragma unroll
  for (int j = 0; j < 8; ++j){
    int col = j*16 + l15;
    float bb = bias[col];
    #pragma unroll
    for (int r = 0; r < 4; ++r){
      int row = wrow + 4*lg + r;
      if (row < M){
        float v = acc[j][r] + bb;
        if (RELU) v = fmaxf(v, 0.f);
        if (EMIT_F32)  out[(size_t)row*128 + col] = v;
        if (EMIT_BF16) out_bf[(size_t)row*128 + col] = f2bf(v);
      }
    }
  }
}

// Decoder (pos+neg fused via blockIdx.y):
// out[p] = relu(concat(h2[u],h2[v]) @ Wd1 + bd1) @ Wd2 + bd2
__global__ __launch_bounds__(256)
void k_decode(const short* __restrict__ h2b, const short* __restrict__ WdP,
              const float* __restrict__ bd1, const float* __restrict__ wd2,
              const float* __restrict__ bd2,
              const int* __restrict__ pos_u, const int* __restrict__ pos_v,
              const int* __restrict__ neg_u, const int* __restrict__ neg_v,
              float* __restrict__ out_pos, float* __restrict__ out_neg, int P)
{
  const int which = blockIdx.y;
  const int* iu = which ? neg_u : pos_u;
  const int* iv = which ? neg_v : pos_v;
  float* out = which ? out_neg : out_pos;

  const int wave = threadIdx.x >> 6;
  const int lane = threadIdx.x & 63;
  const int l15 = lane & 15, lg = lane >> 4;
  const int wbase = blockIdx.x*128 + wave*32;

  int ra0 = wbase + l15;      if (ra0 >= P) ra0 = P - 1;
  int ra1 = wbase + 16 + l15; if (ra1 >= P) ra1 = P - 1;
  int u0 = iu[ra0], v0 = iv[ra0];
  int u1 = iu[ra1], v1 = iv[ra1];

  s16x8 a0[8], a1[8];
  #pragma unroll
  for (int kk = 0; kk < 8; ++kk){
    int kg = kk*32 + 8*lg;
    const short* s0 = (kg < 128) ? h2b + (size_t)u0*128 + kg
                                 : h2b + (size_t)v0*128 + (kg - 128);
    const short* s1 = (kg < 128) ? h2b + (size_t)u1*128 + kg
                                 : h2b + (size_t)v1*128 + (kg - 128);
    a0[kk] = *(const s16x8*)s0;
    a1[kk] = *(const s16x8*)s1;
  }

  const s16x8* Wp = (const s16x8*)WdP;
  f32x4 acc0[8], acc1[8];
  #pragma unroll
  for (int j = 0; j < 8; ++j){
    acc0[j] = (f32x4){0.f,0.f,0.f,0.f};
    acc1[j] = (f32x4){0.f,0.f,0.f,0.f};
  }

  #pragma unroll
  for (int j = 0; j < 8; ++j){
    #pragma unroll
    for (int kk = 0; kk < 8; ++kk){
      s16x8 b = Wp[(j*8 + kk)*64 + lane];
      acc0[j] = __builtin_amdgcn_mfma_f32_16x16x32_bf16(a0[kk], b, acc0[j], 0, 0, 0);
      acc1[j] = __builtin_amdgcn_mfma_f32_16x16x32_bf16(a1[kk], b, acc1[j], 0, 0, 0);
    }
  }

  float part0[4] = {0,0,0,0}, part1[4] = {0,0,0,0};
  #pragma unroll
  for (int j = 0; j < 8; ++j){
    int col = j*16 + l15;
    float bb = bd1[col], ww = wd2[col];
    #pragma unroll
    for (int r = 0; r < 4; ++r){
      part0[r] = fmaf(fmaxf(acc0[j][r] + bb, 0.f), ww, part0[r]);
      part1[r] = fmaf(fmaxf(acc1[j][r] + bb, 0.f), ww, part1[r]);
    }
  }
  #pragma unroll
  for (int off = 1; off < 16; off <<= 1){
    #pragma unroll
    for (int r = 0; r < 4; ++r){
      part0[r] += __shfl_xor(part0[r], off);
      part1[r] += __shfl_xor(part1[r], off);
    }
  }
  if (l15 == 0){
    float b2v = bd2[0];
    int m0 = wbase + 4*lg, m1 = wbase + 16 + 4*lg;
    #pragma unroll
    for (int r = 0; r < 4; ++r){
      if (m0 + r < P) out[m0 + r] = part0[r] + b2v;
      if (m1 + r < P) out[m1 + r] = part1[r] + b2v;
    }
  }
}

extern "C" void kernel_launch(void* const* d_in, const int* in_sizes, int n_in,
                              void* d_out, int out_size, void* d_ws, size_t ws_size,
                              hipStream_t stream){
  const int*   adj   = (const int*)  d_in[0];
  const float* av    = (const float*)d_in[1];
  const float* h     = (const float*)d_in[3];
  const int*   pos_u = (const int*)  d_in[4];
  const int*   pos_v = (const int*)  d_in[5];
  const int*   neg_u = (const int*)  d_in[6];
  const int*   neg_v = (const int*)  d_in[7];
  const float* W1    = (const float*)d_in[8];
  const float* b1    = (const float*)d_in[9];
  const float* W2    = (const float*)d_in[10];
  const float* b2    = (const float*)d_in[11];
  const float* Wd1   = (const float*)d_in[12];
  const float* bd1   = (const float*)d_in[13];
  const float* Wd2   = (const float*)d_in[14];
  const float* bd2   = (const float*)d_in[15];

  const int E = in_sizes[0] / 2;
  const int N = in_sizes[3] / 128;
  const int P = in_sizes[4];
  const int NB = (N + 255) / 256;
  const int n4 = N * 128 / 4;

  auto al = [](size_t x){ return (x + 255) & ~(size_t)255; };
  char* base = (char*)d_ws;
  size_t off = 0;
  int*   rp     = (int*)(base + off);   off = al(off + (size_t)(N+1)*4);
  int*   cursor = (int*)(base + off);   off = al(off + (size_t)N*4);
  int*   bsum   = (int*)(base + off);   off = al(off + (size_t)NB*4);
  int*   boff   = (int*)(base + off);   off = al(off + (size_t)NB*4);
  int2*  ce     = (int2*)(base + off);  off = al(off + (size_t)E*8);
  short* W12h   = (short*)(base + off); off = al(off + (size_t)32768*2);
  short* W12l   = (short*)(base + off); off = al(off + (size_t)32768*2);
  short* WdP    = (short*)(base + off); off = al(off + (size_t)32768*2);
  short* hb     = (short*)(base + off); off = al(off + (size_t)N*128*2);
  short* h1b    = (short*)(base + off); off = al(off + (size_t)N*128*2);
  short* h2b    = (short*)(base + off); off = al(off + (size_t)N*128*2);

  float* scores_pos = (float*)d_out;
  float* scores_neg = scores_pos + P;
  float* h2         = scores_neg + P;   // spmm accumulator + final fp32 output

  hipMemsetAsync(rp, 0, (size_t)(N+1)*4, stream);

  k_count   <<<(E+255)/256, 256, 0, stream>>>(adj, rp, E);
  k_blocksum<<<NB, 256, 0, stream>>>(rp, bsum, N);
  k_scanb   <<<1, 256, 0, stream>>>(bsum, boff, rp + N, NB);
  k_addoff  <<<NB, 256, 0, stream>>>(rp, cursor, boff, N);
  k_scatter <<<(E+255)/256, 256, 0, stream>>>(adj, av, cursor, ce, E);
  k_prep    <<<(n4 + 65536 + 255)/256, 256, 0, stream>>>(h, W1, W2, Wd1, hb, W12h, W12l, WdP, n4);

  // layer 1: bf16 gather spmm -> agg (h2 region), mgemm -> h1b (bf16 only)
  k_spmm<<<(N+15)/16, 256, 0, stream>>>(rp, ce, hb, h2, N);
  k_mgemm<true , false, true ><<<(N+63)/64, 256, 0, stream>>>(h2, W12h, W12l, b1, nullptr, h1b, N);

  // layer 2: bf16 gather spmm -> agg (h2 region), mgemm in-place -> h2 fp32 + h2b
  k_spmm<<<(N+15)/16, 256, 0, stream>>>(rp, ce, h1b, h2, N);
  k_mgemm<false, true , true ><<<(N+63)/64, 256, 0, stream>>>(h2, W12h + 16384, W12l + 16384, b2, h2, h2b, N);

  // decoder (pos & neg in one dispatch)
  dim3 dgrid((P+127)/128, 2);
  k_decode<<<dgrid, 256, 0, stream>>>(h2b, WdP, bd1, Wd2, bd2,
                                      pos_u, pos_v, neg_u, neg_v,
                                      scores_pos, scores_neg, P);
}

// Round 9
// 333.237 us; speedup vs baseline: 2.8719x; 1.0420x over previous
//
#include <hip/hip_runtime.h>

// SparseGraphSAGE: CSR build (count -> hierarchical scan -> scatter int2) ->
// bf16-gather spmm (fused deg) -> split-bf16 MFMA gemm(relu, emit bf16) ->
// bf16-gather spmm -> MFMA gemm(fp32 + bf16 emit) -> bf16-MFMA fused decoder
// with LDS-staged B (Wd1).

typedef float  f32x4 __attribute__((ext_vector_type(4)));
typedef short  s16x8 __attribute__((ext_vector_type(8)));
typedef short  s16x4 __attribute__((ext_vector_type(4)));

__device__ inline short f2bf(float f){
  union { float f; unsigned u; } x; x.f = f;
  unsigned u = x.u;
  return (short)((u + 0x7FFFu + ((u >> 16) & 1u)) >> 16);   // RNE
}
__device__ inline float bf2f(short h){
  union { unsigned u; float f; } c; c.u = ((unsigned)(unsigned short)h) << 16;
  return c.f;
}

__global__ void k_count(const int* __restrict__ idx, int* __restrict__ cnt, int E){
  int e = blockIdx.x*blockDim.x + threadIdx.x;
  if (e >= E) return;
  int2 rc = ((const int2*)idx)[e];
  atomicAdd(&cnt[rc.x], 1);
}

__global__ void k_blocksum(const int* __restrict__ rp, int* __restrict__ bsum, int N){
  int i = blockIdx.x*256 + threadIdx.x;
  int c = (i < N) ? rp[i] : 0;
  #pragma unroll
  for (int off = 1; off < 64; off <<= 1) c += __shfl_xor(c, off);
  __shared__ int s[4];
  if ((threadIdx.x & 63) == 0) s[threadIdx.x >> 6] = c;
  __syncthreads();
  if (threadIdx.x == 0) bsum[blockIdx.x] = s[0] + s[1] + s[2] + s[3];
}

__global__ void k_scanb(const int* __restrict__ bsum, int* __restrict__ boff,
                        int* __restrict__ rpN, int B){
  __shared__ int s[256];
  int t = threadIdx.x;
  int run = 0;
  for (int base = 0; base < B; base += 256){
    int c = (base + t < B) ? bsum[base + t] : 0;
    s[t] = c;
    __syncthreads();
    #pragma unroll
    for (int off = 1; off < 256; off <<= 1){
      int v = s[t];
      int u = (t >= off) ? s[t-off] : 0;
      __syncthreads();
      s[t] = v + u;
      __syncthreads();
    }
    if (base + t < B) boff[base + t] = run + s[t] - c;
    run += s[255];
    __syncthreads();
  }
  if (t == 0) rpN[0] = run;
}

__global__ void k_addoff(int* __restrict__ rp, int* __restrict__ cursor,
                         const int* __restrict__ boff, int N){
  __shared__ int s[256];
  int t = threadIdx.x;
  int i = blockIdx.x*256 + t;
  int c = (i < N) ? rp[i] : 0;
  s[t] = c;
  __syncthreads();
  #pragma unroll
  for (int off = 1; off < 256; off <<= 1){
    int v = s[t];
    int u = (t >= off) ? s[t-off] : 0;
    __syncthreads();
    s[t] = v + u;
    __syncthreads();
  }
  int excl = s[t] - c + boff[blockIdx.x];
  if (i < N){ rp[i] = excl; cursor[i] = excl; }
}

// scatter fused (col, val) pairs: one 8B store per edge
__global__ void k_scatter(const int* __restrict__ idx, const float* __restrict__ vals,
                          int* __restrict__ cursor, int2* __restrict__ ce, int E){
  int e = blockIdx.x*blockDim.x + threadIdx.x;
  if (e >= E) return;
  int2 rc = ((const int2*)idx)[e];
  int p = atomicAdd(&cursor[rc.x], 1);
  ce[p] = make_int2(rc.y, __float_as_int(vals[e]));
}

// prep: h -> bf16 copy; pack W1/W2 split hi/lo; pack Wd1 bf16. One dispatch.
__global__ void k_prep(const float* __restrict__ h, const float* __restrict__ W1,
                       const float* __restrict__ W2, const float* __restrict__ Wd1,
                       short* __restrict__ hb, short* __restrict__ Wh,
                       short* __restrict__ Wl, short* __restrict__ WdP, int n4){
  int gid = blockIdx.x*256 + threadIdx.x;
  if (gid < n4){
    float4 v = ((const float4*)h)[gid];
    s16x4 o; o[0]=f2bf(v.x); o[1]=f2bf(v.y); o[2]=f2bf(v.z); o[3]=f2bf(v.w);
    *(s16x4*)&hb[(size_t)gid*4] = o;
  } else if (gid < n4 + 32768){
    int idx = gid - n4;
    int b = idx & 7, lane = (idx >> 3) & 63, kk = (idx >> 9) & 3, j = (idx >> 11) & 7;
    int m = idx >> 14;
    const float* W = m ? W2 : W1;
    int row = kk*32 + 8*(lane >> 4) + b;
    int col = j*16 + (lane & 15);
    float x = W[row*128 + col];
    short hbit = f2bf(x);
    Wh[idx] = hbit;
    Wl[idx] = f2bf(x - bf2f(hbit));
  } else if (gid < n4 + 65536){
    int idx = gid - n4 - 32768;
    int b = idx & 7, lane = (idx >> 3) & 63, kk = (idx >> 9) & 7, j = (idx >> 12) & 7;
    int row = kk*32 + 8*(lane >> 4) + b;
    int col = j*16 + (lane & 15);
    WdP[idx] = f2bf(Wd1[row*128 + col]);
  }
}

// out[r][:] = (1/clip(sum v,1)) * sum_e v_e * Xb[col_e][:]   (bf16 gather, fp32 accum)
__global__ void k_spmm(const int* __restrict__ rp, const int2* __restrict__ ce,
                       const short* __restrict__ Xb, float* __restrict__ out, int N){
  int r = blockIdx.x*16 + (threadIdx.x >> 4);
  int t = threadIdx.x & 15;
  if (r >= N) return;
  f32x4 a0 = {0.f,0.f,0.f,0.f}, a1 = {0.f,0.f,0.f,0.f};
  float vs0 = 0.f, vs1 = 0.f;
  int e0 = rp[r], e1 = rp[r+1];
  int e = e0;
  for (; e + 3 < e1; e += 4){
    int2 p0 = ce[e], p1 = ce[e+1], p2 = ce[e+2], p3 = ce[e+3];
    s16x8 x0 = *(const s16x8*)&Xb[(size_t)p0.x*128 + t*8];
    s16x8 x1 = *(const s16x8*)&Xb[(size_t)p1.x*128 + t*8];
    s16x8 x2 = *(const s16x8*)&Xb[(size_t)p2.x*128 + t*8];
    s16x8 x3 = *(const s16x8*)&Xb[(size_t)p3.x*128 + t*8];
    float v0 = __int_as_float(p0.y), v1 = __int_as_float(p1.y);
    float v2 = __int_as_float(p2.y), v3 = __int_as_float(p3.y);
    #pragma unroll
    for (int b = 0; b < 4; ++b){
      a0[b] = fmaf(v0, bf2f(x0[b]), a0[b]);   a1[b] = fmaf(v0, bf2f(x0[b+4]), a1[b]);
      a0[b] = fmaf(v1, bf2f(x1[b]), a0[b]);   a1[b] = fmaf(v1, bf2f(x1[b+4]), a1[b]);
      a0[b] = fmaf(v2, bf2f(x2[b]), a0[b]);   a1[b] = fmaf(v2, bf2f(x2[b+4]), a1[b]);
      a0[b] = fmaf(v3, bf2f(x3[b]), a0[b]);   a1[b] = fmaf(v3, bf2f(x3[b+4]), a1[b]);
    }
    vs0 += v0 + v2; vs1 += v1 + v3;
  }
  for (; e < e1; ++e){
    int2 p0 = ce[e];
    s16x8 x0 = *(const s16x8*)&Xb[(size_t)p0.x*128 + t*8];
    float v0 = __int_as_float(p0.y);
    #pragma unroll
    for (int b = 0; b < 4; ++b){
      a0[b] = fmaf(v0, bf2f(x0[b]), a0[b]);
      a1[b] = fmaf(v0, bf2f(x0[b+4]), a1[b]);
    }
    vs0 += v0;
  }
  float di = 1.0f / fmaxf(vs0 + vs1, 1.0f);
  a0 *= di; a1 *= di;
  *(f32x4*)&out[(size_t)r*128 + t*8]     = a0;
  *(f32x4*)&out[(size_t)r*128 + t*8 + 4] = a1;
}

// Split-bf16 MFMA layer GEMM: out = maybe_relu(A @ W + bias), A:[M][128] fp32.
template<bool RELU, bool EMIT_F32, bool EMIT_BF16>
__global__ __launch_bounds__(256)
void k_mgemm(const float* __restrict__ A, const short* __restrict__ Wh,
             const short* __restrict__ Wl, const float* __restrict__ bias,
             float* __restrict__ out, short* __restrict__ out_bf, int M)
{
  const int wave = threadIdx.x >> 6;
  const int lane = threadIdx.x & 63;
  const int l15 = lane & 15, lg = lane >> 4;
  const int wrow = blockIdx.x*64 + wave*16;
  int arow = wrow + l15; if (arow >= M) arow = M - 1;

  s16x8 ah[4], al[4];
  #pragma unroll
  for (int kk = 0; kk < 4; ++kk){
    const float* src = &A[(size_t)arow*128 + kk*32 + 8*lg];
    float4 x0 = *(const float4*)src;
    float4 x1 = *(const float4*)(src + 4);
    float xs[8] = {x0.x,x0.y,x0.z,x0.w,x1.x,x1.y,x1.z,x1.w};
    #pragma unroll
    for (int b = 0; b < 8; ++b){
      short hb = f2bf(xs[b]);
      ah[kk][b] = hb;
      al[kk][b] = f2bf(xs[b] - bf2f(hb));
    }
  }

  const s16x8* WH = (const s16x8*)Wh;
  const s16x8* WL = (const s16x8*)Wl;
  f32x4 acc[8];
  #pragma unroll
  for (int j = 0; j < 8; ++j) acc[j] = (f32x4){0.f,0.f,0.f,0.f};

  #pragma unroll
  for (int j = 0; j < 8; ++j){
    #pragma unroll
    for (int kk = 0; kk < 4; ++kk){
      s16x8 bh = WH[(j*4 + kk)*64 + lane];
      s16x8 bl = WL[(j*4 + kk)*64 + lane];
      acc[j] = __builtin_amdgcn_mfma_f32_16x16x32_bf16(ah[kk], bh, acc[j], 0, 0, 0);
      acc[j] = __builtin_amdgcn_mfma_f32_16x16x32_bf16(al[kk], bh, acc[j], 0, 0, 0);
      acc[j] = __builtin_amdgcn_mfma_f32_16x16x32_bf16(ah[kk], bl, acc[j], 0, 0, 0);
    }
  }

  #pragma unroll
  for (int j = 0; j < 8; ++j){
    int col = j*16 + l15;
    float bb = bias[col];
    #pragma unroll
    for (int r = 0; r < 4; ++r){
      int row = wrow + 4*lg + r;
      if (row < M){
        float v = acc[j][r] + bb;
        if (RELU) v = fmaxf(v, 0.f);
        if (EMIT_F32)  out[(size_t)row*128 + col] = v;
        if (EMIT_BF16) out_bf[(size_t)row*128 + col] = f2bf(v);
      }
    }
  }
}

// Decoder (pos+neg fused via blockIdx.y), B staged in LDS:
// out[p] = relu(concat(h2[u],h2[v]) @ Wd1 + bd1) @ Wd2 + bd2
__global__ __launch_bounds__(256)
void k_decode(const short* __restrict__ h2b, const short* __restrict__ WdP,
              const float* __restrict__ bd1, const float* __restrict__ wd2,
              const float* __restrict__ bd2,
              const int* __restrict__ pos_u, const int* __restrict__ pos_v,
              const int* __restrict__ neg_u, const int* __restrict__ neg_v,
              float* __restrict__ out_pos, float* __restrict__ out_neg, int P)
{
  __shared__ short Bs[32768];          // 64 KB: full packed Wd1

  const int which = blockIdx.y;
  const int* iu = which ? neg_u : pos_u;
  const int* iv = which ? neg_v : pos_v;
  float* out = which ? out_neg : out_pos;

  const int wave = threadIdx.x >> 6;
  const int lane = threadIdx.x & 63;
  const int l15 = lane & 15, lg = lane >> 4;
  const int wbase = blockIdx.x*128 + wave*32;

  int ra0 = wbase + l15;      if (ra0 >= P) ra0 = P - 1;
  int ra1 = wbase + 16 + l15; if (ra1 >= P) ra1 = P - 1;
  int u0 = iu[ra0], v0 = iv[ra0];
  int u1 = iu[ra1], v1 = iv[ra1];

  // A-gathers issued first: latency hides under the LDS fill + barrier.
  s16x8 a0[8], a1[8];
  #pragma unroll
  for (int kk = 0; kk < 8; ++kk){
    int kg = kk*32 + 8*lg;
    const short* s0 = (kg < 128) ? h2b + (size_t)u0*128 + kg
                                 : h2b + (size_t)v0*128 + (kg - 128);
    const short* s1 = (kg < 128) ? h2b + (size_t)u1*128 + kg
                                 : h2b + (size_t)v1*128 + (kg - 128);
    a0[kk] = *(const s16x8*)s0;
    a1[kk] = *(const s16x8*)s1;
  }

  // cooperative B fill: 65536 B / 256 thr = 16 x 16B each, coalesced
  {
    const int4* src = (const int4*)WdP;
    int4* dst = (int4*)Bs;
    #pragma unroll
    for (int i = 0; i < 16; ++i)
      dst[threadIdx.x + i*256] = src[threadIdx.x + i*256];
  }
  __syncthreads();

  const s16x8* Wp = (const s16x8*)Bs;
  f32x4 acc0[8], acc1[8];
  #pragma unroll
  for (int j = 0; j < 8; ++j){
    acc0[j] = (f32x4){0.f,0.f,0.f,0.f};
    acc1[j] = (f32x4){0.f,0.f,0.f,0.f};
  }

  #pragma unroll
  for (int j = 0; j < 8; ++j){
    #pragma unroll
    for (int kk = 0; kk < 8; ++kk){
      s16x8 b = Wp[(j*8 + kk)*64 + lane];
      acc0[j] = __builtin_amdgcn_mfma_f32_16x16x32_bf16(a0[kk], b, acc0[j], 0, 0, 0);
      acc1[j] = __builtin_amdgcn_mfma_f32_16x16x32_bf16(a1[kk], b, acc1[j], 0, 0, 0);
    }
  }

  float part0[4] = {0,0,0,0}, part1[4] = {0,0,0,0};
  #pragma unroll
  for (int j = 0; j < 8; ++j){
    int col = j*16 + l15;
    float bb = bd1[col], ww = wd2[col];
    #pragma unroll
    for (int r = 0; r < 4; ++r){
      part0[r] = fmaf(fmaxf(acc0[j][r] + bb, 0.f), ww, part0[r]);
      part1[r] = fmaf(fmaxf(acc1[j][r] + bb, 0.f), ww, part1[r]);
    }
  }
  #pragma unroll
  for (int off = 1; off < 16; off <<= 1){
    #pragma unroll
    for (int r = 0; r < 4; ++r){
      part0[r] += __shfl_xor(part0[r], off);
      part1[r] += __shfl_xor(part1[r], off);
    }
  }
  if (l15 == 0){
    float b2v = bd2[0];
    int m0 = wbase + 4*lg, m1 = wbase + 16 + 4*lg;
    #pragma unroll
    for (int r = 0; r < 4; ++r){
      if (m0 + r < P) out[m0 + r] = part0[r] + b2v;
      if (m1 + r < P) out[m1 + r] = part1[r] + b2v;
    }
  }
}

extern "C" void kernel_launch(void* const* d_in, const int* in_sizes, int n_in,
                              void* d_out, int out_size, void* d_ws, size_t ws_size,
                              hipStream_t stream){
  const int*   adj   = (const int*)  d_in[0];
  const float* av    = (const float*)d_in[1];
  const float* h     = (const float*)d_in[3];
  const int*   pos_u = (const int*)  d_in[4];
  const int*   pos_v = (const int*)  d_in[5];
  const int*   neg_u = (const int*)  d_in[6];
  const int*   neg_v = (const int*)  d_in[7];
  const float* W1    = (const float*)d_in[8];
  const float* b1    = (const float*)d_in[9];
  const float* W2    = (const float*)d_in[10];
  const float* b2    = (const float*)d_in[11];
  const float* Wd1   = (const float*)d_in[12];
  const float* bd1   = (const float*)d_in[13];
  const float* Wd2   = (const float*)d_in[14];
  const float* bd2   = (const float*)d_in[15];

  const int E = in_sizes[0] / 2;
  const int N = in_sizes[3] / 128;
  const int P = in_sizes[4];
  const int NB = (N + 255) / 256;
  const int n4 = N * 128 / 4;

  auto al = [](size_t x){ return (x + 255) & ~(size_t)255; };
  char* base = (char*)d_ws;
  size_t off = 0;
  int*   rp     = (int*)(base + off);   off = al(off + (size_t)(N+1)*4);
  int*   cursor = (int*)(base + off);   off = al(off + (size_t)N*4);
  int*   bsum   = (int*)(base + off);   off = al(off + (size_t)NB*4);
  int*   boff   = (int*)(base + off);   off = al(off + (size_t)NB*4);
  int2*  ce     = (int2*)(base + off);  off = al(off + (size_t)E*8);
  short* W12h   = (short*)(base + off); off = al(off + (size_t)32768*2);
  short* W12l   = (short*)(base + off); off = al(off + (size_t)32768*2);
  short* WdP    = (short*)(base + off); off = al(off + (size_t)32768*2);
  short* hb     = (short*)(base + off); off = al(off + (size_t)N*128*2);
  short* h1b    = (short*)(base + off); off = al(off + (size_t)N*128*2);
  short* h2b    = (short*)(base + off); off = al(off + (size_t)N*128*2);

  float* scores_pos = (float*)d_out;
  float* scores_neg = scores_pos + P;
  float* h2         = scores_neg + P;   // spmm accumulator + final fp32 output

  hipMemsetAsync(rp, 0, (size_t)(N+1)*4, stream);

  k_count   <<<(E+255)/256, 256, 0, stream>>>(adj, rp, E);
  k_blocksum<<<NB, 256, 0, stream>>>(rp, bsum, N);
  k_scanb   <<<1, 256, 0, stream>>>(bsum, boff, rp + N, NB);
  k_addoff  <<<NB, 256, 0, stream>>>(rp, cursor, boff, N);
  k_scatter <<<(E+255)/256, 256, 0, stream>>>(adj, av, cursor, ce, E);
  k_prep    <<<(n4 + 65536 + 255)/256, 256, 0, stream>>>(h, W1, W2, Wd1, hb, W12h, W12l, WdP, n4);

  // layer 1: bf16 gather spmm -> agg (h2 region), mgemm -> h1b (bf16 only)
  k_spmm<<<(N+15)/16, 256, 0, stream>>>(rp, ce, hb, h2, N);
  k_mgemm<true , false, true ><<<(N+63)/64, 256, 0, stream>>>(h2, W12h, W12l, b1, nullptr, h1b, N);

  // layer 2: bf16 gather spmm -> agg (h2 region), mgemm in-place -> h2 fp32 + h2b
  k_spmm<<<(N+15)/16, 256, 0, stream>>>(rp, ce, h1b, h2, N);
  k_mgemm<false, true , true ><<<(N+63)/64, 256, 0, stream>>>(h2, W12h + 16384, W12l + 16384, b2, h2, h2b, N);

  // decoder (pos & neg in one dispatch, LDS-staged B)
  dim3 dgrid((P+127)/128, 2);
  k_decode<<<dgrid, 256, 0, stream>>>(h2b, WdP, bd1, Wd2, bd2,
                                      pos_u, pos_v, neg_u, neg_v,
                                      scores_pos, scores_neg, P);
}

// Round 10
// 308.648 us; speedup vs baseline: 3.1007x; 1.0797x over previous
//
#include <hip/hip_runtime.h>

// SparseGraphSAGE: CSR build (count+rank -> hierarchical scan -> atomic-free scatter)
// -> bf16-gather spmm (fused deg) -> split-bf16 MFMA gemm(relu, emit bf16) ->
// bf16-gather spmm -> MFMA gemm(fp32 + bf16 emit) -> bf16-MFMA fused decoder
// with LDS-staged B (Wd1).

typedef float  f32x4 __attribute__((ext_vector_type(4)));
typedef short  s16x8 __attribute__((ext_vector_type(8)));
typedef short  s16x4 __attribute__((ext_vector_type(4)));

__device__ inline short f2bf(float f){
  union { float f; unsigned u; } x; x.f = f;
  unsigned u = x.u;
  return (short)((u + 0x7FFFu + ((u >> 16) & 1u)) >> 16);   // RNE
}
__device__ inline float bf2f(short h){
  union { unsigned u; float f; } c; c.u = ((unsigned)(unsigned short)h) << 16;
  return c.f;
}

// count + per-edge rank (old counter value). 4 edges/thread: 4 independent
// atomic chains per thread for latency hiding.
__global__ void k_count(const int* __restrict__ idx, int* __restrict__ cnt,
                        int* __restrict__ rank, int E, int S){
  int i = blockIdx.x*256 + threadIdx.x;
  int e0 = i, e1 = i + S, e2 = i + 2*S, e3 = i + 3*S;
  int2 rc0, rc1, rc2, rc3;
  if (e0 < E) rc0 = ((const int2*)idx)[e0];
  if (e1 < E) rc1 = ((const int2*)idx)[e1];
  if (e2 < E) rc2 = ((const int2*)idx)[e2];
  if (e3 < E) rc3 = ((const int2*)idx)[e3];
  int r0 = 0, r1 = 0, r2 = 0, r3 = 0;
  if (e0 < E) r0 = atomicAdd(&cnt[rc0.x], 1);
  if (e1 < E) r1 = atomicAdd(&cnt[rc1.x], 1);
  if (e2 < E) r2 = atomicAdd(&cnt[rc2.x], 1);
  if (e3 < E) r3 = atomicAdd(&cnt[rc3.x], 1);
  if (e0 < E) rank[e0] = r0;
  if (e1 < E) rank[e1] = r1;
  if (e2 < E) rank[e2] = r2;
  if (e3 < E) rank[e3] = r3;
}

__global__ void k_blocksum(const int* __restrict__ rp, int* __restrict__ bsum, int N){
  int i = blockIdx.x*256 + threadIdx.x;
  int c = (i < N) ? rp[i] : 0;
  #pragma unroll
  for (int off = 1; off < 64; off <<= 1) c += __shfl_xor(c, off);
  __shared__ int s[4];
  if ((threadIdx.x & 63) == 0) s[threadIdx.x >> 6] = c;
  __syncthreads();
  if (threadIdx.x == 0) bsum[blockIdx.x] = s[0] + s[1] + s[2] + s[3];
}

__global__ void k_scanb(const int* __restrict__ bsum, int* __restrict__ boff,
                        int* __restrict__ rpN, int B){
  __shared__ int s[256];
  int t = threadIdx.x;
  int run = 0;
  for (int base = 0; base < B; base += 256){
    int c = (base + t < B) ? bsum[base + t] : 0;
    s[t] = c;
    __syncthreads();
    #pragma unroll
    for (int off = 1; off < 256; off <<= 1){
      int v = s[t];
      int u = (t >= off) ? s[t-off] : 0;
      __syncthreads();
      s[t] = v + u;
      __syncthreads();
    }
    if (base + t < B) boff[base + t] = run + s[t] - c;
    run += s[255];
    __syncthreads();
  }
  if (t == 0) rpN[0] = run;
}

__global__ void k_addoff(int* __restrict__ rp, const int* __restrict__ boff, int N){
  __shared__ int s[256];
  int t = threadIdx.x;
  int i = blockIdx.x*256 + t;
  int c = (i < N) ? rp[i] : 0;
  s[t] = c;
  __syncthreads();
  #pragma unroll
  for (int off = 1; off < 256; off <<= 1){
    int v = s[t];
    int u = (t >= off) ? s[t-off] : 0;
    __syncthreads();
    s[t] = v + u;
    __syncthreads();
  }
  if (i < N) rp[i] = s[t] - c + boff[blockIdx.x];
}

// atomic-free scatter: p = rp[row] + rank[e]; fire-and-forget 8B store.
__global__ void k_scatter(const int* __restrict__ idx, const float* __restrict__ vals,
                          const int* __restrict__ rp, const int* __restrict__ rank,
                          int2* __restrict__ ce, int E, int S){
  int i = blockIdx.x*256 + threadIdx.x;
  #pragma unroll
  for (int q = 0; q < 4; ++q){
    int e = i + q*S;
    if (e < E){
      int2 rc = ((const int2*)idx)[e];
      int p = rp[rc.x] + rank[e];
      ce[p] = make_int2(rc.y, __float_as_int(vals[e]));
    }
  }
}

// prep: h -> bf16 copy; pack W1/W2 split hi/lo; pack Wd1 bf16. One dispatch.
__global__ void k_prep(const float* __restrict__ h, const float* __restrict__ W1,
                       const float* __restrict__ W2, const float* __restrict__ Wd1,
                       short* __restrict__ hb, short* __restrict__ Wh,
                       short* __restrict__ Wl, short* __restrict__ WdP, int n4){
  int gid = blockIdx.x*256 + threadIdx.x;
  if (gid < n4){
    float4 v = ((const float4*)h)[gid];
    s16x4 o; o[0]=f2bf(v.x); o[1]=f2bf(v.y); o[2]=f2bf(v.z); o[3]=f2bf(v.w);
    *(s16x4*)&hb[(size_t)gid*4] = o;
  } else if (gid < n4 + 32768){
    int idx = gid - n4;
    int b = idx & 7, lane = (idx >> 3) & 63, kk = (idx >> 9) & 3, j = (idx >> 11) & 7;
    int m = idx >> 14;
    const float* W = m ? W2 : W1;
    int row = kk*32 + 8*(lane >> 4) + b;
    int col = j*16 + (lane & 15);
    float x = W[row*128 + col];
    short hbit = f2bf(x);
    Wh[idx] = hbit;
    Wl[idx] = f2bf(x - bf2f(hbit));
  } else if (gid < n4 + 65536){
    int idx = gid - n4 - 32768;
    int b = idx & 7, lane = (idx >> 3) & 63, kk = (idx >> 9) & 7, j = (idx >> 12) & 7;
    int row = kk*32 + 8*(lane >> 4) + b;
    int col = j*16 + (lane & 15);
    WdP[idx] = f2bf(Wd1[row*128 + col]);
  }
}

// out[r][:] = (1/clip(sum v,1)) * sum_e v_e * Xb[col_e][:]   (bf16 gather, fp32 accum)
__global__ void k_spmm(const int* __restrict__ rp, const int2* __restrict__ ce,
                       const short* __restrict__ Xb, float* __restrict__ out, int N){
  int r = blockIdx.x*16 + (threadIdx.x >> 4);
  int t = threadIdx.x & 15;
  if (r >= N) return;
  f32x4 a0 = {0.f,0.f,0.f,0.f}, a1 = {0.f,0.f,0.f,0.f};
  float vs0 = 0.f, vs1 = 0.f;
  int e0 = rp[r], e1 = rp[r+1];
  int e = e0;
  for (; e + 3 < e1; e += 4){
    int2 p0 = ce[e], p1 = ce[e+1], p2 = ce[e+2], p3 = ce[e+3];
    s16x8 x0 = *(const s16x8*)&Xb[(size_t)p0.x*128 + t*8];
    s16x8 x1 = *(const s16x8*)&Xb[(size_t)p1.x*128 + t*8];
    s16x8 x2 = *(const s16x8*)&Xb[(size_t)p2.x*128 + t*8];
    s16x8 x3 = *(const s16x8*)&Xb[(size_t)p3.x*128 + t*8];
    float v0 = __int_as_float(p0.y), v1 = __int_as_float(p1.y);
    float v2 = __int_as_float(p2.y), v3 = __int_as_float(p3.y);
    #pragma unroll
    for (int b = 0; b < 4; ++b){
      a0[b] = fmaf(v0, bf2f(x0[b]), a0[b]);   a1[b] = fmaf(v0, bf2f(x0[b+4]), a1[b]);
      a0[b] = fmaf(v1, bf2f(x1[b]), a0[b]);   a1[b] = fmaf(v1, bf2f(x1[b+4]), a1[b]);
      a0[b] = fmaf(v2, bf2f(x2[b]), a0[b]);   a1[b] = fmaf(v2, bf2f(x2[b+4]), a1[b]);
      a0[b] = fmaf(v3, bf2f(x3[b]), a0[b]);   a1[b] = fmaf(v3, bf2f(x3[b+4]), a1[b]);
    }
    vs0 += v0 + v2; vs1 += v1 + v3;
  }
  for (; e < e1; ++e){
    int2 p0 = ce[e];
    s16x8 x0 = *(const s16x8*)&Xb[(size_t)p0.x*128 + t*8];
    float v0 = __int_as_float(p0.y);
    #pragma unroll
    for (int b = 0; b < 4; ++b){
      a0[b] = fmaf(v0, bf2f(x0[b]), a0[b]);
      a1[b] = fmaf(v0, bf2f(x0[b+4]), a1[b]);
    }
    vs0 += v0;
  }
  float di = 1.0f / fmaxf(vs0 + vs1, 1.0f);
  a0 *= di; a1 *= di;
  *(f32x4*)&out[(size_t)r*128 + t*8]     = a0;
  *(f32x4*)&out[(size_t)r*128 + t*8 + 4] = a1;
}

// Split-bf16 MFMA layer GEMM: out = maybe_relu(A @ W + bias), A:[M][128] fp32.
template<bool RELU, bool EMIT_F32, bool EMIT_BF16>
__global__ __launch_bounds__(256)
void k_mgemm(const float* __restrict__ A, const short* __restrict__ Wh,
             const short* __restrict__ Wl, const float* __restrict__ bias,
             float* __restrict__ out, short* __restrict__ out_bf, int M)
{
  const int wave = threadIdx.x >> 6;
  const int lane = threadIdx.x & 63;
  const int l15 = lane & 15, lg = lane >> 4;
  const int wrow = blockIdx.x*64 + wave*16;
  int arow = wrow + l15; if (arow >= M) arow = M - 1;

  s16x8 ah[4], al[4];
  #pragma unroll
  for (int kk = 0; kk < 4; ++kk){
    const float* src = &A[(size_t)arow*128 + kk*32 + 8*lg];
    float4 x0 = *(const float4*)src;
    float4 x1 = *(const float4*)(src + 4);
    float xs[8] = {x0.x,x0.y,x0.z,x0.w,x1.x,x1.y,x1.z,x1.w};
    #pragma unroll
    for (int b = 0; b < 8; ++b){
      short hb = f2bf(xs[b]);
      ah[kk][b] = hb;
      al[kk][b] = f2bf(xs[b] - bf2f(hb));
    }
  }

  const s16x8* WH = (const s16x8*)Wh;
  const s16x8* WL = (const s16x8*)Wl;
  f32x4 acc[8];
  #pragma unroll
  for (int j = 0; j < 8; ++j) acc[j] = (f32x4){0.f,0.f,0.f,0.f};

  #pragma unroll
  for (int j = 0; j < 8; ++j){
    #pragma unroll
    for (int kk = 0; kk < 4; ++kk){
      s16x8 bh = WH[(j*4 + kk)*64 + lane];
      s16x8 bl = WL[(j*4 + kk)*64 + lane];
      acc[j] = __builtin_amdgcn_mfma_f32_16x16x32_bf16(ah[kk], bh, acc[j], 0, 0, 0);
      acc[j] = __builtin_amdgcn_mfma_f32_16x16x32_bf16(al[kk], bh, acc[j], 0, 0, 0);
      acc[j] = __builtin_amdgcn_mfma_f32_16x16x32_bf16(ah[kk], bl, acc[j], 0, 0, 0);
    }
  }

  #pragma unroll
  for (int j = 0; j < 8; ++j){
    int col = j*16 + l15;
    float bb = bias[col];
    #pragma unroll
    for (int r = 0; r < 4; ++r){
      int row = wrow + 4*lg + r;
      if (row < M){
        float v = acc[j][r] + bb;
        if (RELU) v = fmaxf(v, 0.f);
        if (EMIT_F32)  out[(size_t)row*128 + col] = v;
        if (EMIT_BF16) out_bf[(size_t)row*128 + col] = f2bf(v);
      }
    }
  }
}

// Decoder (pos+neg fused via blockIdx.y), B staged in LDS:
// out[p] = relu(concat(h2[u],h2[v]) @ Wd1 + bd1) @ Wd2 + bd2
__global__ __launch_bounds__(256)
void k_decode(const short* __restrict__ h2b, const short* __restrict__ WdP,
              const float* __restrict__ bd1, const float* __restrict__ wd2,
              const float* __restrict__ bd2,
              const int* __restrict__ pos_u, const int* __restrict__ pos_v,
              const int* __restrict__ neg_u, const int* __restrict__ neg_v,
              float* __restrict__ out_pos, float* __restrict__ out_neg, int P)
{
  __shared__ short Bs[32768];          // 64 KB: full packed Wd1

  const int which = blockIdx.y;
  const int* iu = which ? neg_u : pos_u;
  const int* iv = which ? neg_v : pos_v;
  float* out = which ? out_neg : out_pos;

  const int wave = threadIdx.x >> 6;
  const int lane = threadIdx.x & 63;
  const int l15 = lane & 15, lg = lane >> 4;
  const int wbase = blockIdx.x*128 + wave*32;

  int ra0 = wbase + l15;      if (ra0 >= P) ra0 = P - 1;
  int ra1 = wbase + 16 + l15; if (ra1 >= P) ra1 = P - 1;
  int u0 = iu[ra0], v0 = iv[ra0];
  int u1 = iu[ra1], v1 = iv[ra1];

  // A-gathers issued first: latency hides under the LDS fill + barrier.
  s16x8 a0[8], a1[8];
  #pragma unroll
  for (int kk = 0; kk < 8; ++kk){
    int kg = kk*32 + 8*lg;
    const short* s0 = (kg < 128) ? h2b + (size_t)u0*128 + kg
                                 : h2b + (size_t)v0*128 + (kg - 128);
    const short* s1 = (kg < 128) ? h2b + (size_t)u1*128 + kg
                                 : h2b + (size_t)v1*128 + (kg - 128);
    a0[kk] = *(const s16x8*)s0;
    a1[kk] = *(const s16x8*)s1;
  }

  // cooperative B fill: 65536 B / 256 thr = 16 x 16B each, coalesced
  {
    const int4* src = (const int4*)WdP;
    int4* dst = (int4*)Bs;
    #pragma unroll
    for (int i = 0; i < 16; ++i)
      dst[threadIdx.x + i*256] = src[threadIdx.x + i*256];
  }
  __syncthreads();

  const s16x8* Wp = (const s16x8*)Bs;
  f32x4 acc0[8], acc1[8];
  #pragma unroll
  for (int j = 0; j < 8; ++j){
    acc0[j] = (f32x4){0.f,0.f,0.f,0.f};
    acc1[j] = (f32x4){0.f,0.f,0.f,0.f};
  }

  #pragma unroll
  for (int j = 0; j < 8; ++j){
    #pragma unroll
    for (int kk = 0; kk < 8; ++kk){
      s16x8 b = Wp[(j*8 + kk)*64 + lane];
      acc0[j] = __builtin_amdgcn_mfma_f32_16x16x32_bf16(a0[kk], b, acc0[j], 0, 0, 0);
      acc1[j] = __builtin_amdgcn_mfma_f32_16x16x32_bf16(a1[kk], b, acc1[j], 0, 0, 0);
    }
  }

  float part0[4] = {0,0,0,0}, part1[4] = {0,0,0,0};
  #pragma unroll
  for (int j = 0; j < 8; ++j){
    int col = j*16 + l15;
    float bb = bd1[col], ww = wd2[col];
    #pragma unroll
    for (int r = 0; r < 4; ++r){
      part0[r] = fmaf(fmaxf(acc0[j][r] + bb, 0.f), ww, part0[r]);
      part1[r] = fmaf(fmaxf(acc1[j][r] + bb, 0.f), ww, part1[r]);
    }
  }
  #pragma unroll
  for (int off = 1; off < 16; off <<= 1){
    #pragma unroll
    for (int r = 0; r < 4; ++r){
      part0[r] += __shfl_xor(part0[r], off);
      part1[r] += __shfl_xor(part1[r], off);
    }
  }
  if (l15 == 0){
    float b2v = bd2[0];
    int m0 = wbase + 4*lg, m1 = wbase + 16 + 4*lg;
    #pragma unroll
    for (int r = 0; r < 4; ++r){
      if (m0 + r < P) out[m0 + r] = part0[r] + b2v;
      if (m1 + r < P) out[m1 + r] = part1[r] + b2v;
    }
  }
}

extern "C" void kernel_launch(void* const* d_in, const int* in_sizes, int n_in,
                              void* d_out, int out_size, void* d_ws, size_t ws_size,
                              hipStream_t stream){
  const int*   adj   = (const int*)  d_in[0];
  const float* av    = (const float*)d_in[1];
  const float* h     = (const float*)d_in[3];
  const int*   pos_u = (const int*)  d_in[4];
  const int*   pos_v = (const int*)  d_in[5];
  const int*   neg_u = (const int*)  d_in[6];
  const int*   neg_v = (const int*)  d_in[7];
  const float* W1    = (const float*)d_in[8];
  const float* b1    = (const float*)d_in[9];
  const float* W2    = (const float*)d_in[10];
  const float* b2    = (const float*)d_in[11];
  const float* Wd1   = (const float*)d_in[12];
  const float* bd1   = (const float*)d_in[13];
  const float* Wd2   = (const float*)d_in[14];
  const float* bd2   = (const float*)d_in[15];

  const int E = in_sizes[0] / 2;
  const int N = in_sizes[3] / 128;
  const int P = in_sizes[4];
  const int NB = (N + 255) / 256;
  const int n4 = N * 128 / 4;

  auto al = [](size_t x){ return (x + 255) & ~(size_t)255; };
  char* base = (char*)d_ws;
  size_t off = 0;
  int*   rp     = (int*)(base + off);   off = al(off + (size_t)(N+1)*4);
  int*   rank   = (int*)(base + off);   off = al(off + (size_t)E*4);
  int*   bsum   = (int*)(base + off);   off = al(off + (size_t)NB*4);
  int*   boff   = (int*)(base + off);   off = al(off + (size_t)NB*4);
  int2*  ce     = (int2*)(base + off);  off = al(off + (size_t)E*8);
  short* W12h   = (short*)(base + off); off = al(off + (size_t)32768*2);
  short* W12l   = (short*)(base + off); off = al(off + (size_t)32768*2);
  short* WdP    = (short*)(base + off); off = al(off + (size_t)32768*2);
  short* hb     = (short*)(base + off); off = al(off + (size_t)N*128*2);
  short* h1b    = (short*)(base + off); off = al(off + (size_t)N*128*2);
  short* h2b    = (short*)(base + off); off = al(off + (size_t)N*128*2);

  float* scores_pos = (float*)d_out;
  float* scores_neg = scores_pos + P;
  float* h2         = scores_neg + P;   // spmm accumulator + final fp32 output

  hipMemsetAsync(rp, 0, (size_t)(N+1)*4, stream);

  // CSR build: count(+rank) -> scan -> atomic-free scatter
  const int EG = ((E + 3) / 4 + 255) / 256;   // blocks so ~4 edges/thread
  const int S  = EG * 256;
  k_count   <<<EG, 256, 0, stream>>>(adj, rp, rank, E, S);
  k_blocksum<<<NB, 256, 0, stream>>>(rp, bsum, N);
  k_scanb   <<<1, 256, 0, stream>>>(bsum, boff, rp + N, NB);
  k_addoff  <<<NB, 256, 0, stream>>>(rp, boff, N);
  k_scatter <<<EG, 256, 0, stream>>>(adj, av, rp, rank, ce, E, S);
  k_prep    <<<(n4 + 65536 + 255)/256, 256, 0, stream>>>(h, W1, W2, Wd1, hb, W12h, W12l, WdP, n4);

  // layer 1: bf16 gather spmm -> agg (h2 region), mgemm -> h1b (bf16 only)
  k_spmm<<<(N+15)/16, 256, 0, stream>>>(rp, ce, hb, h2, N);
  k_mgemm<true , false, true ><<<(N+63)/64, 256, 0, stream>>>(h2, W12h, W12l, b1, nullptr, h1b, N);

  // layer 2: bf16 gather spmm -> agg (h2 region), mgemm in-place -> h2 fp32 + h2b
  k_spmm<<<(N+15)/16, 256, 0, stream>>>(rp, ce, h1b, h2, N);
  k_mgemm<false, true , true ><<<(N+63)/64, 256, 0, stream>>>(h2, W12h + 16384, W12l + 16384, b2, h2, h2b, N);

  // decoder (pos & neg in one dispatch, LDS-staged B)
  dim3 dgrid((P+127)/128, 2);
  k_decode<<<dgrid, 256, 0, stream>>>(h2b, WdP, bd1, Wd2, bd2,
                                      pos_u, pos_v, neg_u, neg_v,
                                      scores_pos, scores_neg, P);
}

// Round 11
// 295.518 us; speedup vs baseline: 3.2385x; 1.0444x over previous
//
#include <hip/hip_runtime.h>

// SparseGraphSAGE: CSR build (count+rank -> blocksum -> addoff(self-prefix) ->
// fused scatter+prep) -> fused layer kernel (bf16-gather spmm -> LDS ->
// split-bf16 MFMA gemm) x2 -> bf16-MFMA fused decoder with LDS-staged B.

typedef float  f32x4 __attribute__((ext_vector_type(4)));
typedef short  s16x8 __attribute__((ext_vector_type(8)));
typedef short  s16x4 __attribute__((ext_vector_type(4)));

__device__ inline short f2bf(float f){
  union { float f; unsigned u; } x; x.f = f;
  unsigned u = x.u;
  return (short)((u + 0x7FFFu + ((u >> 16) & 1u)) >> 16);   // RNE
}
__device__ inline float bf2f(short h){
  union { unsigned u; float f; } c; c.u = ((unsigned)(unsigned short)h) << 16;
  return c.f;
}

// count + per-edge rank (old counter value). 4 independent atomic chains/thread.
__global__ void k_count(const int* __restrict__ idx, int* __restrict__ cnt,
                        int* __restrict__ rank, int E, int S){
  int i = blockIdx.x*256 + threadIdx.x;
  int e0 = i, e1 = i + S, e2 = i + 2*S, e3 = i + 3*S;
  int2 rc0, rc1, rc2, rc3;
  if (e0 < E) rc0 = ((const int2*)idx)[e0];
  if (e1 < E) rc1 = ((const int2*)idx)[e1];
  if (e2 < E) rc2 = ((const int2*)idx)[e2];
  if (e3 < E) rc3 = ((const int2*)idx)[e3];
  int r0 = 0, r1 = 0, r2 = 0, r3 = 0;
  if (e0 < E) r0 = atomicAdd(&cnt[rc0.x], 1);
  if (e1 < E) r1 = atomicAdd(&cnt[rc1.x], 1);
  if (e2 < E) r2 = atomicAdd(&cnt[rc2.x], 1);
  if (e3 < E) r3 = atomicAdd(&cnt[rc3.x], 1);
  if (e0 < E) rank[e0] = r0;
  if (e1 < E) rank[e1] = r1;
  if (e2 < E) rank[e2] = r2;
  if (e3 < E) rank[e3] = r3;
}

__global__ void k_blocksum(const int* __restrict__ rp, int* __restrict__ bsum, int N){
  int i = blockIdx.x*256 + threadIdx.x;
  int c = (i < N) ? rp[i] : 0;
  #pragma unroll
  for (int off = 1; off < 64; off <<= 1) c += __shfl_xor(c, off);
  __shared__ int s[4];
  if ((threadIdx.x & 63) == 0) s[threadIdx.x >> 6] = c;
  __syncthreads();
  if (threadIdx.x == 0) bsum[blockIdx.x] = s[0] + s[1] + s[2] + s[3];
}

// local scan + self-computed prefix over bsum (no separate scanb kernel)
__global__ void k_addoff(int* __restrict__ rp, const int* __restrict__ bsum,
                         int NB, int N){
  __shared__ int s[256];
  __shared__ int pre_s, tot_s;
  const int t = threadIdx.x;
  const int bid = blockIdx.x;

  int pre = 0, tot = 0;
  for (int j = t; j < NB; j += 256){
    int b = bsum[j];
    tot += b;
    if (j < bid) pre += b;
  }
  #pragma unroll
  for (int off = 1; off < 64; off <<= 1){
    pre += __shfl_xor(pre, off);
    tot += __shfl_xor(tot, off);
  }
  __shared__ int ps[4], ts[4];
  if ((t & 63) == 0){ ps[t >> 6] = pre; ts[t >> 6] = tot; }
  __syncthreads();
  if (t == 0){
    pre_s = ps[0] + ps[1] + ps[2] + ps[3];
    tot_s = ts[0] + ts[1] + ts[2] + ts[3];
  }
  __syncthreads();

  int i = bid*256 + t;
  int c = (i < N) ? rp[i] : 0;
  s[t] = c;
  __syncthreads();
  #pragma unroll
  for (int off = 1; off < 256; off <<= 1){
    int v = s[t];
    int u = (t >= off) ? s[t-off] : 0;
    __syncthreads();
    s[t] = v + u;
    __syncthreads();
  }
  if (i < N) rp[i] = s[t] - c + pre_s;
  if (bid == NB-1 && t == 0) rp[N] = tot_s;
}

// fused: blocks [0,EG): atomic-free scatter; blocks [EG,..): prep
// (h->bf16, pack W1/W2 split hi/lo, pack Wd1 bf16)
__global__ void k_sp(const int* __restrict__ idx, const float* __restrict__ vals,
                     const int* __restrict__ rp, const int* __restrict__ rank,
                     int2* __restrict__ ce, int E, int S, int EG,
                     const float* __restrict__ h, const float* __restrict__ W1,
                     const float* __restrict__ W2, const float* __restrict__ Wd1,
                     short* __restrict__ hb, short* __restrict__ Wh,
                     short* __restrict__ Wl, short* __restrict__ WdP, int n4){
  int bid = blockIdx.x;
  if (bid < EG){
    int i = bid*256 + threadIdx.x;
    #pragma unroll
    for (int q = 0; q < 4; ++q){
      int e = i + q*S;
      if (e < E){
        int2 rc = ((const int2*)idx)[e];
        int p = rp[rc.x] + rank[e];
        ce[p] = make_int2(rc.y, __float_as_int(vals[e]));
      }
    }
    return;
  }
  int gid = (bid - EG)*256 + threadIdx.x;
  if (gid < n4){
    float4 v = ((const float4*)h)[gid];
    s16x4 o; o[0]=f2bf(v.x); o[1]=f2bf(v.y); o[2]=f2bf(v.z); o[3]=f2bf(v.w);
    *(s16x4*)&hb[(size_t)gid*4] = o;
  } else if (gid < n4 + 32768){
    int idx2 = gid - n4;
    int b = idx2 & 7, lane = (idx2 >> 3) & 63, kk = (idx2 >> 9) & 3, j = (idx2 >> 11) & 7;
    int m = idx2 >> 14;
    const float* W = m ? W2 : W1;
    int row = kk*32 + 8*(lane >> 4) + b;
    int col = j*16 + (lane & 15);
    float x = W[row*128 + col];
    short hbit = f2bf(x);
    Wh[idx2] = hbit;
    Wl[idx2] = f2bf(x - bf2f(hbit));
  } else if (gid < n4 + 65536){
    int idx2 = gid - n4 - 32768;
    int b = idx2 & 7, lane = (idx2 >> 3) & 63, kk = (idx2 >> 9) & 7, j = (idx2 >> 12) & 7;
    int row = kk*32 + 8*(lane >> 4) + b;
    int col = j*16 + (lane & 15);
    WdP[idx2] = f2bf(Wd1[row*128 + col]);
  }
}

// Fused layer: phase1 spmm (bf16 gather, fp32 accum) -> LDS tile ->
// phase2 split-bf16 MFMA gemm with bias/relu epilogue.
// 64 rows/block; phase1: 16 thr/row x 4 row-groups; phase2: 4 waves x 16 rows.
template<bool RELU, bool EMIT_F32, bool EMIT_BF16>
__global__ __launch_bounds__(256)
void k_layer(const int* __restrict__ rp, const int2* __restrict__ ce,
             const short* __restrict__ Xb, const short* __restrict__ Wh,
             const short* __restrict__ Wl, const float* __restrict__ bias,
             float* __restrict__ outf, short* __restrict__ outb, int N)
{
  __shared__ float As[64][132];   // +4 pad: spread LDS banks
  const int tid = threadIdx.x;
  const int brow = blockIdx.x*64;

  // ---- phase 1: spmm for 64 rows ----
  {
    const int t = tid & 15;
    const int rloc = tid >> 4;    // 0..15
    for (int g = 0; g < 4; ++g){
      int lrow = g*16 + rloc;
      int row = brow + lrow;
      f32x4 a0 = {0.f,0.f,0.f,0.f}, a1 = {0.f,0.f,0.f,0.f};
      float vs0 = 0.f, vs1 = 0.f;
      if (row < N){
        int e0 = rp[row], e1 = rp[row+1];
        int e = e0;
        for (; e + 3 < e1; e += 4){
          int2 p0 = ce[e], p1 = ce[e+1], p2 = ce[e+2], p3 = ce[e+3];
          s16x8 x0 = *(const s16x8*)&Xb[(size_t)p0.x*128 + t*8];
          s16x8 x1 = *(const s16x8*)&Xb[(size_t)p1.x*128 + t*8];
          s16x8 x2 = *(const s16x8*)&Xb[(size_t)p2.x*128 + t*8];
          s16x8 x3 = *(const s16x8*)&Xb[(size_t)p3.x*128 + t*8];
          float v0 = __int_as_float(p0.y), v1 = __int_as_float(p1.y);
          float v2 = __int_as_float(p2.y), v3 = __int_as_float(p3.y);
          #pragma unroll
          for (int b = 0; b < 4; ++b){
            a0[b] = fmaf(v0, bf2f(x0[b]), a0[b]);   a1[b] = fmaf(v0, bf2f(x0[b+4]), a1[b]);
            a0[b] = fmaf(v1, bf2f(x1[b]), a0[b]);   a1[b] = fmaf(v1, bf2f(x1[b+4]), a1[b]);
            a0[b] = fmaf(v2, bf2f(x2[b]), a0[b]);   a1[b] = fmaf(v2, bf2f(x2[b+4]), a1[b]);
            a0[b] = fmaf(v3, bf2f(x3[b]), a0[b]);   a1[b] = fmaf(v3, bf2f(x3[b+4]), a1[b]);
          }
          vs0 += v0 + v2; vs1 += v1 + v3;
        }
        for (; e < e1; ++e){
          int2 p0 = ce[e];
          s16x8 x0 = *(const s16x8*)&Xb[(size_t)p0.x*128 + t*8];
          float v0 = __int_as_float(p0.y);
          #pragma unroll
          for (int b = 0; b < 4; ++b){
            a0[b] = fmaf(v0, bf2f(x0[b]), a0[b]);
            a1[b] = fmaf(v0, bf2f(x0[b+4]), a1[b]);
          }
          vs0 += v0;
        }
        float di = 1.0f / fmaxf(vs0 + vs1, 1.0f);
        a0 *= di; a1 *= di;
      }
      *(f32x4*)&As[lrow][t*8]     = a0;
      *(f32x4*)&As[lrow][t*8 + 4] = a1;
    }
  }
  __syncthreads();

  // ---- phase 2: split-bf16 MFMA gemm, A from LDS ----
  const int wave = tid >> 6;
  const int lane = tid & 63;
  const int l15 = lane & 15, lg = lane >> 4;
  const int arow = wave*16 + l15;

  s16x8 ah[4], al[4];
  #pragma unroll
  for (int kk = 0; kk < 4; ++kk){
    const float* src = &As[arow][kk*32 + 8*lg];
    float4 x0 = *(const float4*)src;
    float4 x1 = *(const float4*)(src + 4);
    float xs[8] = {x0.x,x0.y,x0.z,x0.w,x1.x,x1.y,x1.z,x1.w};
    #pragma unroll
    for (int b = 0; b < 8; ++b){
      short hb2 = f2bf(xs[b]);
      ah[kk][b] = hb2;
      al[kk][b] = f2bf(xs[b] - bf2f(hb2));
    }
  }

  const s16x8* WH = (const s16x8*)Wh;
  const s16x8* WL = (const s16x8*)Wl;
  f32x4 acc[8];
  #pragma unroll
  for (int j = 0; j < 8; ++j) acc[j] = (f32x4){0.f,0.f,0.f,0.f};

  #pragma unroll
  for (int j = 0; j < 8; ++j){
    #pragma unroll
    for (int kk = 0; kk < 4; ++kk){
      s16x8 bh = WH[(j*4 + kk)*64 + lane];
      s16x8 bl = WL[(j*4 + kk)*64 + lane];
      acc[j] = __builtin_amdgcn_mfma_f32_16x16x32_bf16(ah[kk], bh, acc[j], 0, 0, 0);
      acc[j] = __builtin_amdgcn_mfma_f32_16x16x32_bf16(al[kk], bh, acc[j], 0, 0, 0);
      acc[j] = __builtin_amdgcn_mfma_f32_16x16x32_bf16(ah[kk], bl, acc[j], 0, 0, 0);
    }
  }

  #pragma unroll
  for (int j = 0; j < 8; ++j){
    int col = j*16 + l15;
    float bb = bias[col];
    #pragma unroll
    for (int r = 0; r < 4; ++r){
      int row = brow + wave*16 + 4*lg + r;
      if (row < N){
        float v = acc[j][r] + bb;
        if (RELU) v = fmaxf(v, 0.f);
        if (EMIT_F32)  outf[(size_t)row*128 + col] = v;
        if (EMIT_BF16) outb[(size_t)row*128 + col] = f2bf(v);
      }
    }
  }
}

// Decoder (pos+neg fused via blockIdx.y), B staged in LDS:
// out[p] = relu(concat(h2[u],h2[v]) @ Wd1 + bd1) @ Wd2 + bd2
__global__ __launch_bounds__(256)
void k_decode(const short* __restrict__ h2b, const short* __restrict__ WdP,
              const float* __restrict__ bd1, const float* __restrict__ wd2,
              const float* __restrict__ bd2,
              const int* __restrict__ pos_u, const int* __restrict__ pos_v,
              const int* __restrict__ neg_u, const int* __restrict__ neg_v,
              float* __restrict__ out_pos, float* __restrict__ out_neg, int P)
{
  __shared__ short Bs[32768];          // 64 KB: full packed Wd1

  const int which = blockIdx.y;
  const int* iu = which ? neg_u : pos_u;
  const int* iv = which ? neg_v : pos_v;
  float* out = which ? out_neg : out_pos;

  const int wave = threadIdx.x >> 6;
  const int lane = threadIdx.x & 63;
  const int l15 = lane & 15, lg = lane >> 4;
  const int wbase = blockIdx.x*128 + wave*32;

  int ra0 = wbase + l15;      if (ra0 >= P) ra0 = P - 1;
  int ra1 = wbase + 16 + l15; if (ra1 >= P) ra1 = P - 1;
  int u0 = iu[ra0], v0 = iv[ra0];
  int u1 = iu[ra1], v1 = iv[ra1];

  // A-gathers issued first: latency hides under the LDS fill + barrier.
  s16x8 a0[8], a1[8];
  #pragma unroll
  for (int kk = 0; kk < 8; ++kk){
    int kg = kk*32 + 8*lg;
    const short* s0 = (kg < 128) ? h2b + (size_t)u0*128 + kg
                                 : h2b + (size_t)v0*128 + (kg - 128);
    const short* s1 = (kg < 128) ? h2b + (size_t)u1*128 + kg
                                 : h2b + (size_t)v1*128 + (kg - 128);
    a0[kk] = *(const s16x8*)s0;
    a1[kk] = *(const s16x8*)s1;
  }

  // cooperative B fill: 65536 B / 256 thr = 16 x 16B each, coalesced
  {
    const int4* src = (const int4*)WdP;
    int4* dst = (int4*)Bs;
    #pragma unroll
    for (int i = 0; i < 16; ++i)
      dst[threadIdx.x + i*256] = src[threadIdx.x + i*256];
  }
  __syncthreads();

  const s16x8* Wp = (const s16x8*)Bs;
  f32x4 acc0[8], acc1[8];
  #pragma unroll
  for (int j = 0; j < 8; ++j){
    acc0[j] = (f32x4){0.f,0.f,0.f,0.f};
    acc1[j] = (f32x4){0.f,0.f,0.f,0.f};
  }

  #pragma unroll
  for (int j = 0; j < 8; ++j){
    #pragma unroll
    for (int kk = 0; kk < 8; ++kk){
      s16x8 b = Wp[(j*8 + kk)*64 + lane];
      acc0[j] = __builtin_amdgcn_mfma_f32_16x16x32_bf16(a0[kk], b, acc0[j], 0, 0, 0);
      acc1[j] = __builtin_amdgcn_mfma_f32_16x16x32_bf16(a1[kk], b, acc1[j], 0, 0, 0);
    }
  }

  float part0[4] = {0,0,0,0}, part1[4] = {0,0,0,0};
  #pragma unroll
  for (int j = 0; j < 8; ++j){
    int col = j*16 + l15;
    float bb = bd1[col], ww = wd2[col];
    #pragma unroll
    for (int r = 0; r < 4; ++r){
      part0[r] = fmaf(fmaxf(acc0[j][r] + bb, 0.f), ww, part0[r]);
      part1[r] = fmaf(fmaxf(acc1[j][r] + bb, 0.f), ww, part1[r]);
    }
  }
  #pragma unroll
  for (int off = 1; off < 16; off <<= 1){
    #pragma unroll
    for (int r = 0; r < 4; ++r){
      part0[r] += __shfl_xor(part0[r], off);
      part1[r] += __shfl_xor(part1[r], off);
    }
  }
  if (l15 == 0){
    float b2v = bd2[0];
    int m0 = wbase + 4*lg, m1 = wbase + 16 + 4*lg;
    #pragma unroll
    for (int r = 0; r < 4; ++r){
      if (m0 + r < P) out[m0 + r] = part0[r] + b2v;
      if (m1 + r < P) out[m1 + r] = part1[r] + b2v;
    }
  }
}

extern "C" void kernel_launch(void* const* d_in, const int* in_sizes, int n_in,
                              void* d_out, int out_size, void* d_ws, size_t ws_size,
                              hipStream_t stream){
  const int*   adj   = (const int*)  d_in[0];
  const float* av    = (const float*)d_in[1];
  const float* h     = (const float*)d_in[3];
  const int*   pos_u = (const int*)  d_in[4];
  const int*   pos_v = (const int*)  d_in[5];
  const int*   neg_u = (const int*)  d_in[6];
  const int*   neg_v = (const int*)  d_in[7];
  const float* W1    = (const float*)d_in[8];
  const float* b1    = (const float*)d_in[9];
  const float* W2    = (const float*)d_in[10];
  const float* b2    = (const float*)d_in[11];
  const float* Wd1   = (const float*)d_in[12];
  const float* bd1   = (const float*)d_in[13];
  const float* Wd2   = (const float*)d_in[14];
  const float* bd2   = (const float*)d_in[15];

  const int E = in_sizes[0] / 2;
  const int N = in_sizes[3] / 128;
  const int P = in_sizes[4];
  const int NB = (N + 255) / 256;
  const int n4 = N * 128 / 4;

  auto al = [](size_t x){ return (x + 255) & ~(size_t)255; };
  char* base = (char*)d_ws;
  size_t off = 0;
  int*   rp     = (int*)(base + off);   off = al(off + (size_t)(N+1)*4);
  int*   rank   = (int*)(base + off);   off = al(off + (size_t)E*4);
  int*   bsum   = (int*)(base + off);   off = al(off + (size_t)NB*4);
  int2*  ce     = (int2*)(base + off);  off = al(off + (size_t)E*8);
  short* W12h   = (short*)(base + off); off = al(off + (size_t)32768*2);
  short* W12l   = (short*)(base + off); off = al(off + (size_t)32768*2);
  short* WdP    = (short*)(base + off); off = al(off + (size_t)32768*2);
  short* hb     = (short*)(base + off); off = al(off + (size_t)N*128*2);
  short* h1b    = (short*)(base + off); off = al(off + (size_t)N*128*2);
  short* h2b    = (short*)(base + off); off = al(off + (size_t)N*128*2);

  float* scores_pos = (float*)d_out;
  float* scores_neg = scores_pos + P;
  float* h2         = scores_neg + P;   // final fp32 h2 output (d_out)

  hipMemsetAsync(rp, 0, (size_t)(N+1)*4, stream);

  // CSR build
  const int EG = ((E + 3) / 4 + 255) / 256;   // blocks, ~4 edges/thread
  const int S  = EG * 256;
  const int PB = (n4 + 65536 + 255) / 256;    // prep blocks
  k_count   <<<EG, 256, 0, stream>>>(adj, rp, rank, E, S);
  k_blocksum<<<NB, 256, 0, stream>>>(rp, bsum, N);
  k_addoff  <<<NB, 256, 0, stream>>>(rp, bsum, NB, N);
  k_sp      <<<EG + PB, 256, 0, stream>>>(adj, av, rp, rank, ce, E, S, EG,
                                          h, W1, W2, Wd1, hb, W12h, W12l, WdP, n4);

  // layer 1: fused spmm+gemm -> h1b (bf16 only)
  k_layer<true , false, true ><<<(N+63)/64, 256, 0, stream>>>(
      rp, ce, hb, W12h, W12l, b1, nullptr, h1b, N);

  // layer 2: fused spmm+gemm -> h2 fp32 (d_out) + h2b
  k_layer<false, true , true ><<<(N+63)/64, 256, 0, stream>>>(
      rp, ce, h1b, W12h + 16384, W12l + 16384, b2, h2, h2b, N);

  // decoder (pos & neg in one dispatch, LDS-staged B)
  dim3 dgrid((P+127)/128, 2);
  k_decode<<<dgrid, 256, 0, stream>>>(h2b, WdP, bd1, Wd2, bd2,
                                      pos_u, pos_v, neg_u, neg_v,
                                      scores_pos, scores_neg, P);
}